// Round 14
// baseline (612.140 us; speedup 1.0000x reference)
//
#include <hip/hip_runtime.h>
#include <cstdint>
#include <cstddef>

#define NPTS 8192
#define BATCH 16
#define MS 128
#define KNB 64
#define NBLK (BATCH * MS)   // 2048
#define KNNBLK 240          // knn-role blocks in the fused cooperative grid
#define NQUAD 512           // 2048 samples / 4 per quad
// dynamic LDS partition (bytes)
#define SQV_Q 8224                      // floats per quarter (swizzle pad)
#define WL_OFF (4 * SQV_Q * 4)          // 131584
#define SELK_OFF (WL_OFF + 8192)        // 139776
#define DYN_BYTES (SELK_OFF + 2048)     // 141824

// ---------------- DPP wave reductions (VALU-speed, no LDS crossbar) ----------
__device__ __forceinline__ float dpp_wave_max_f32(float v) {
  v = fmaxf(v, __int_as_float(__builtin_amdgcn_update_dpp((int)0xff800000, __float_as_int(v), 0x111, 0xf, 0xf, false)));
  v = fmaxf(v, __int_as_float(__builtin_amdgcn_update_dpp((int)0xff800000, __float_as_int(v), 0x112, 0xf, 0xf, false)));
  v = fmaxf(v, __int_as_float(__builtin_amdgcn_update_dpp((int)0xff800000, __float_as_int(v), 0x114, 0xf, 0xf, false)));
  v = fmaxf(v, __int_as_float(__builtin_amdgcn_update_dpp((int)0xff800000, __float_as_int(v), 0x118, 0xf, 0xf, false)));
  v = fmaxf(v, __int_as_float(__builtin_amdgcn_update_dpp((int)0xff800000, __float_as_int(v), 0x142, 0xa, 0xf, false)));
  v = fmaxf(v, __int_as_float(__builtin_amdgcn_update_dpp((int)0xff800000, __float_as_int(v), 0x143, 0xc, 0xf, false)));
  return v;  // lane 63
}

__device__ __forceinline__ float dpp_wave_min_f32(float v) {
  v = fminf(v, __int_as_float(__builtin_amdgcn_update_dpp(0x7f800000, __float_as_int(v), 0x111, 0xf, 0xf, false)));
  v = fminf(v, __int_as_float(__builtin_amdgcn_update_dpp(0x7f800000, __float_as_int(v), 0x112, 0xf, 0xf, false)));
  v = fminf(v, __int_as_float(__builtin_amdgcn_update_dpp(0x7f800000, __float_as_int(v), 0x114, 0xf, 0xf, false)));
  v = fminf(v, __int_as_float(__builtin_amdgcn_update_dpp(0x7f800000, __float_as_int(v), 0x118, 0xf, 0xf, false)));
  v = fminf(v, __int_as_float(__builtin_amdgcn_update_dpp(0x7f800000, __float_as_int(v), 0x142, 0xa, 0xf, false)));
  v = fminf(v, __int_as_float(__builtin_amdgcn_update_dpp(0x7f800000, __float_as_int(v), 0x143, 0xc, 0xf, false)));
  return v;  // lane 63
}

__device__ __forceinline__ unsigned dpp_wave_min_u32(unsigned v) {
  unsigned o;
  o = (unsigned)__builtin_amdgcn_update_dpp((int)0xffffffffu, (int)v, 0x111, 0xf, 0xf, false); v = (o < v) ? o : v;
  o = (unsigned)__builtin_amdgcn_update_dpp((int)0xffffffffu, (int)v, 0x112, 0xf, 0xf, false); v = (o < v) ? o : v;
  o = (unsigned)__builtin_amdgcn_update_dpp((int)0xffffffffu, (int)v, 0x114, 0xf, 0xf, false); v = (o < v) ? o : v;
  o = (unsigned)__builtin_amdgcn_update_dpp((int)0xffffffffu, (int)v, 0x118, 0xf, 0xf, false); v = (o < v) ? o : v;
  o = (unsigned)__builtin_amdgcn_update_dpp((int)0xffffffffu, (int)v, 0x142, 0xa, 0xf, false); v = (o < v) ? o : v;
  o = (unsigned)__builtin_amdgcn_update_dpp((int)0xffffffffu, (int)v, 0x143, 0xc, 0xf, false); v = (o < v) ? o : v;
  return v;  // lane 63
}

__device__ __forceinline__ float dpp_row_max_f32(float v) {  // lane 15 of each row
  v = fmaxf(v, __int_as_float(__builtin_amdgcn_update_dpp((int)0xff800000, __float_as_int(v), 0x111, 0xf, 0xf, false)));
  v = fmaxf(v, __int_as_float(__builtin_amdgcn_update_dpp((int)0xff800000, __float_as_int(v), 0x112, 0xf, 0xf, false)));
  v = fmaxf(v, __int_as_float(__builtin_amdgcn_update_dpp((int)0xff800000, __float_as_int(v), 0x114, 0xf, 0xf, false)));
  v = fmaxf(v, __int_as_float(__builtin_amdgcn_update_dpp((int)0xff800000, __float_as_int(v), 0x118, 0xf, 0xf, false)));
  return v;
}

__device__ __forceinline__ unsigned dpp_row_min_u32(unsigned v) {  // lane 15 of each row
  unsigned o;
  o = (unsigned)__builtin_amdgcn_update_dpp((int)0xffffffffu, (int)v, 0x111, 0xf, 0xf, false); v = (o < v) ? o : v;
  o = (unsigned)__builtin_amdgcn_update_dpp((int)0xffffffffu, (int)v, 0x112, 0xf, 0xf, false); v = (o < v) ? o : v;
  o = (unsigned)__builtin_amdgcn_update_dpp((int)0xffffffffu, (int)v, 0x114, 0xf, 0xf, false); v = (o < v) ? o : v;
  o = (unsigned)__builtin_amdgcn_update_dpp((int)0xffffffffu, (int)v, 0x118, 0xf, 0xf, false); v = (o < v) ? o : v;
  return v;
}

// ======================= fused FPS + kNN (cooperative) =======================
// Blocks 0..15: fps role (round-11 verified math, 128 iters) + device-scope
// progress[b] release-store after each sp[it] write.
// Blocks 16..255: 240 knn blocks; each runs the round-12 verified per-sample
// knn in 4 independent 256-thread quarters (4 batches x same m = one "quad"),
// 2-3 quads per block ordered by m; t0 spins (acquire) until the 4 batches'
// progress > m. Co-residency guaranteed by cooperative launch -> no deadlock.
// Per-sample arithmetic/selection byte-identical to rounds 11-13.
#define FPS_STEP(J)                                                        \
  {                                                                        \
    const float4 p = pts4[J * 1024 + t];                                   \
    const float dx = p.x - lx;                                             \
    const float dy = p.y - ly;                                             \
    const float dz = p.z - lz;                                             \
    const float d = dx * dx + dy * dy + dz * dz;                           \
    md##J = fminf(md##J, d);                                               \
  }

#define FPS_RESCAN(J)                                                      \
  if (md##J == wv) best = (unsigned)(J * 1024 + t);

__global__ __launch_bounds__(1024, 4) void fk_kernel(const float* __restrict__ pos,
                                                     const float* __restrict__ xf,
                                                     float* __restrict__ sp,
                                                     float* __restrict__ gf0,
                                                     float* __restrict__ sqsel,
                                                     int* __restrict__ prog) {
#pragma clang fp contract(off)
  extern __shared__ char dynls[];
  const int blk = blockIdx.x;
  const int tid = threadIdx.x;
  if (blk < BATCH) {
    // ------------------------------ fps role ------------------------------
    float4* pts4 = reinterpret_cast<float4*>(dynls);
    __shared__ float wval[2][16];
    __shared__ unsigned widx[2][16];
    const int b = blk;
    const float* P = pos + (size_t)b * NPTS * 3;
    const int t = tid;
    const int wave = t >> 6;
    const int lane = t & 63;
    float md0 = 1e10f, md1 = 1e10f, md2 = 1e10f, md3 = 1e10f;
    float md4 = 1e10f, md5 = 1e10f, md6 = 1e10f, md7 = 1e10f;
    for (int i = t; i < NPTS; i += 1024)
      pts4[i] = make_float4(P[i * 3 + 0], P[i * 3 + 1], P[i * 3 + 2], 0.f);
    float lx = P[0], ly = P[1], lz = P[2];
    __syncthreads();
    for (int it = 0; it < MS; ++it) {
      if (t == 0) {
        sp[((size_t)b * MS + it) * 3 + 0] = lx;
        sp[((size_t)b * MS + it) * 3 + 1] = ly;
        sp[((size_t)b * MS + it) * 3 + 2] = lz;
        __hip_atomic_store(&prog[b], it + 1, __ATOMIC_RELEASE,
                           __HIP_MEMORY_SCOPE_AGENT);
      }
      FPS_STEP(0) FPS_STEP(1) FPS_STEP(2) FPS_STEP(3)
      FPS_STEP(4) FPS_STEP(5) FPS_STEP(6) FPS_STEP(7)
      const float m01 = fmaxf(md0, md1), m23 = fmaxf(md2, md3);
      const float m45 = fmaxf(md4, md5), m67 = fmaxf(md6, md7);
      const float bv = fmaxf(fmaxf(m01, m23), fmaxf(m45, m67));
      const float wv = __int_as_float(
          __builtin_amdgcn_readlane(__float_as_int(dpp_wave_max_f32(bv)), 63));
      unsigned best = 0xffffffffu;
      if (bv == wv) {
        FPS_RESCAN(7) FPS_RESCAN(6) FPS_RESCAN(5) FPS_RESCAN(4)
        FPS_RESCAN(3) FPS_RESCAN(2) FPS_RESCAN(1) FPS_RESCAN(0)
      }
      const unsigned wi =
          (unsigned)__builtin_amdgcn_readlane((int)dpp_wave_min_u32(best), 63);
      const int par = it & 1;
      if (lane == 0) { wval[par][wave] = wv; widx[par][wave] = wi; }
      __syncthreads();
      const float a = wval[par][lane & 15];
      const float Mx = __int_as_float(
          __builtin_amdgcn_readlane(__float_as_int(dpp_row_max_f32(a)), 15));
      const unsigned c2 = (a == Mx) ? widx[par][lane & 15] : 0xffffffffu;
      const unsigned idx =
          (unsigned)__builtin_amdgcn_readlane((int)dpp_row_min_u32(c2), 15);
      const float4 c = pts4[idx];
      lx = c.x; ly = c.y; lz = c.z;
    }
  } else {
    // ------------------------------ knn role ------------------------------
    const int k = blk - BATCH;  // 0..239
    const int q = tid >> 8;     // quarter 0..3
    const int t = tid & 255;    // thread-in-quarter
    const int wave = t >> 6;    // wave-in-quarter 0..3
    const int lane = tid & 63;  // HW lane
    float* sqv = reinterpret_cast<float*>(dynls) + q * SQV_Q;
    unsigned long long* wl =
        reinterpret_cast<unsigned long long*>(dynls + WL_OFF) + (size_t)q * 256;
    unsigned long long* selk =
        reinterpret_cast<unsigned long long*>(dynls + SELK_OFF) + (size_t)q * 64;
    for (int Q = k; Q < NQUAD; Q += KNNBLK) {
      const int m = Q >> 2;
      const int g = Q & 3;
      const int batch = 4 * g + q;
      if (tid == 0) {
        for (int bb = 0; bb < 4; ++bb)
          while (__hip_atomic_load(&prog[4 * g + bb], __ATOMIC_ACQUIRE,
                                   __HIP_MEMORY_SCOPE_AGENT) <= m) {}
      }
      __syncthreads();
      (void)__hip_atomic_load(&prog[batch], __ATOMIC_ACQUIRE,
                              __HIP_MEMORY_SCOPE_AGENT);  // visibility edge
      const int bm = batch * MS + m;
      const float* P = pos + (size_t)batch * NPTS * 3;
      const float sx = sp[bm * 3 + 0], sy = sp[bm * 3 + 1], sz = sp[bm * 3 + 2];
      const float nsp = sx * sx + sy * sy + sz * sz;
      // stage distances (swizzled) + fold per-thread candidate
      float cv;
      unsigned ci;
      {
        unsigned long long k0 = ~0ULL;
        for (int j = 0; j < 32; ++j) {
          const int i = j * 256 + t;
          const float qx = P[i * 3 + 0], qy = P[i * 3 + 1], qz = P[i * 3 + 2];
          const float npos = qx * qx + qy * qy + qz * qz;
          const float dt = sx * qx + sy * qy + sz * qz;
          float sq = (nsp + npos) - 2.0f * dt;  // ||a||^2+||b||^2-2ab order
          sq = fmaxf(sq, 0.0f);
          sqv[i + j] = sq;  // swizzle: i>>8 == j
          const unsigned long long key =
              ((unsigned long long)__float_as_uint(sq) << 32) | (unsigned)i;
          if (key < k0) k0 = key;
        }
        cv = __uint_as_float((unsigned)(k0 >> 32));
        ci = (unsigned)k0;
      }
      __syncthreads();
      // 64 wave-local rounds (no block barriers)
      unsigned cmask = 0u;
      for (int round = 0; round < KNB; ++round) {
        const float wv = __int_as_float(
            __builtin_amdgcn_readlane(__float_as_int(dpp_wave_min_f32(cv)), 63));
        const unsigned sel = (cv == wv) ? ci : 0xffffffffu;
        const unsigned wi =
            (unsigned)__builtin_amdgcn_readlane((int)dpp_wave_min_u32(sel), 63);
        if (lane == 0)
          wl[wave * 64 + round] =
              ((unsigned long long)__float_as_uint(wv) << 32) | wi;
        const int col = (int)(wi & 255u);
        const int ownerLane = col & 63;
        const unsigned jsel = wi >> 8;
        if (lane == ownerLane) cmask |= (1u << jsel);
        const unsigned omask =
            (unsigned)__builtin_amdgcn_readlane((int)cmask, ownerLane);
        float v = __uint_as_float(0x7f800000u);
        unsigned ii = 0xffffffffu;
        if (lane < 32 && !((omask >> lane) & 1u)) {
          const int i = lane * 256 + col;
          v = sqv[i + lane];
          ii = (unsigned)i;
        }
        const float mv = __int_as_float(
            __builtin_amdgcn_readlane(__float_as_int(dpp_wave_min_f32(v)), 63));
        const unsigned s2 = (v == mv) ? ii : 0xffffffffu;
        const unsigned mi =
            (unsigned)__builtin_amdgcn_readlane((int)dpp_wave_min_u32(s2), 63);
        if (lane == ownerLane) { cv = mv; ci = mi; }
      }
      __syncthreads();
      // exact merge by parallel ranking (distinct keys -> permutation)
      {
        const int w = wave, r = lane;
        const unsigned long long e = wl[w * 64 + r];
        int rank = r;
#pragma unroll
        for (int w2 = 0; w2 < 4; ++w2) {
          if (w2 == w) continue;
          int lo = 0;
#pragma unroll
          for (int step = 32; step > 0; step >>= 1)
            if (lo + step <= KNB && wl[w2 * 64 + lo + step - 1] < e) lo += step;
          rank += lo;
        }
        if (rank < KNB) selk[rank] = e;
      }
      __syncthreads();
      if (t < KNB) {
        const unsigned long long e = selk[t];
        const int i = (int)(e & 0xffffffffu);
        const float* X = xf + (size_t)batch * NPTS * 3;
        const size_t base = ((size_t)bm * KNB + t) * 6;
        gf0[base + 0] = P[i * 3 + 0] - sx;
        gf0[base + 1] = P[i * 3 + 1] - sy;
        gf0[base + 2] = P[i * 3 + 2] - sz;
        gf0[base + 3] = X[i * 3 + 0];
        gf0[base + 4] = X[i * 3 + 1];
        gf0[base + 5] = X[i * 3 + 2];
        sqsel[(size_t)bm * KNB + t] = __uint_as_float((unsigned)(e >> 32));
      }
      __syncthreads();  // before restaging sqv next quad
    }
  }
}

// ================================================================ chain
__global__ __launch_bounds__(256) void l1_kernel(
    const float* __restrict__ gf0, const float* __restrict__ W0,
    const float* __restrict__ B0,
    float* __restrict__ psum, float* __restrict__ psq,
    float* __restrict__ y1pre) {
  __shared__ float in6[64 * 8];
  __shared__ float wbuf[384];
  __shared__ float out[64 * 65];
  const int blk = blockIdx.x;
  const int t = threadIdx.x;
  const float* G = gf0 + (size_t)blk * 384;
  for (int i = t; i < 384; i += 256) in6[(i / 6) * 8 + (i % 6)] = G[i];
  for (int i = t; i < 384; i += 256) wbuf[i] = W0[i];
  __syncthreads();
  const int r = t >> 2;
  const int c0 = (t & 3) * 16;
  float acc[16];
#pragma unroll
  for (int j = 0; j < 16; ++j) acc[j] = B0[c0 + j];
  for (int cin = 0; cin < 6; ++cin) {
    const float a = in6[r * 8 + cin];
#pragma unroll
    for (int j = 0; j < 16; ++j) acc[j] = fmaf(a, wbuf[cin * 64 + c0 + j], acc[j]);
  }
#pragma unroll
  for (int j = 0; j < 16; ++j) out[r * 65 + c0 + j] = acc[j];
  __syncthreads();
  if (t < 64) {
    float s = 0.f, q = 0.f;
    for (int r2 = 0; r2 < 64; ++r2) { const float v = out[r2 * 65 + t]; s += v; q += v * v; }
    psum[(size_t)t * NBLK + blk] = s;
    psq[(size_t)t * NBLK + blk] = q;
  }
  float* Y = y1pre + (size_t)blk * 4096;
  for (int i = t; i < 4096; i += 256) Y[i] = out[(i >> 6) * 65 + (i & 63)];
}

__global__ __launch_bounds__(256) void l2_kernel(
    const float* __restrict__ ypre, const float* __restrict__ sc,
    const float* __restrict__ sh, const float* __restrict__ W1,
    const float* __restrict__ B1,
    float* __restrict__ psum, float* __restrict__ psq,
    float* __restrict__ yout) {
  __shared__ float As[64 * 68];
  __shared__ float Bs[64 * 64];
  __shared__ float out[64 * 68];
  const int blk = blockIdx.x;
  const int t = threadIdx.x;
  const float* Y = ypre + (size_t)blk * 4096;
  for (int i = t; i < 4096; i += 256) {
    const int c = i & 63;
    As[(i >> 6) * 68 + c] = fmaxf(fmaf(Y[i], sc[c], sh[c]), 0.f);
  }
  for (int i = t; i < 4096; i += 256) Bs[i] = W1[i];
  __syncthreads();
  const int tr = t >> 4;
  const int tc4 = (t & 15) * 4;
  float acc[4][4];
#pragma unroll
  for (int s = 0; s < 4; ++s)
#pragma unroll
    for (int j = 0; j < 4; ++j) acc[s][j] = B1[tc4 + j];
  for (int k0 = 0; k0 < 64; k0 += 4) {
    float4 av[4];
#pragma unroll
    for (int s = 0; s < 4; ++s)
      av[s] = *reinterpret_cast<const float4*>(&As[(tr + 16 * s) * 68 + k0]);
#pragma unroll
    for (int kk = 0; kk < 4; ++kk) {
      const float4 bv = *reinterpret_cast<const float4*>(&Bs[(k0 + kk) * 64 + tc4]);
#pragma unroll
      for (int s = 0; s < 4; ++s) {
        const float a = (kk == 0) ? av[s].x : (kk == 1) ? av[s].y
                       : (kk == 2) ? av[s].z : av[s].w;
        acc[s][0] = fmaf(a, bv.x, acc[s][0]);
        acc[s][1] = fmaf(a, bv.y, acc[s][1]);
        acc[s][2] = fmaf(a, bv.z, acc[s][2]);
        acc[s][3] = fmaf(a, bv.w, acc[s][3]);
      }
    }
  }
#pragma unroll
  for (int s = 0; s < 4; ++s) {
    float4 o;
    o.x = acc[s][0]; o.y = acc[s][1]; o.z = acc[s][2]; o.w = acc[s][3];
    *reinterpret_cast<float4*>(&out[(tr + 16 * s) * 68 + tc4]) = o;
  }
  __syncthreads();
  if (t < 64) {
    float s = 0.f, q = 0.f;
    for (int r2 = 0; r2 < 64; ++r2) { const float v = out[r2 * 68 + t]; s += v; q += v * v; }
    psum[(size_t)t * NBLK + blk] = s;
    psq[(size_t)t * NBLK + blk] = q;
  }
  float* O = yout + (size_t)blk * 4096;
  for (int i = t; i < 4096; i += 256) O[i] = out[(i >> 6) * 68 + (i & 63)];
}

__global__ __launch_bounds__(256) void l3_kernel(
    const float* __restrict__ ypre, const float* __restrict__ sc,
    const float* __restrict__ sh, const float* __restrict__ W2,
    const float* __restrict__ B2,
    float* __restrict__ psum, float* __restrict__ psq,
    float* __restrict__ yout) {
  __shared__ float As[64 * 68];
  __shared__ float Bs[64 * 64];
  __shared__ float out[64 * 68];
  const int blk = blockIdx.x;
  const int t = threadIdx.x;
  const float* Y = ypre + (size_t)blk * 4096;
  for (int i = t; i < 4096; i += 256) {
    const int c = i & 63;
    As[(i >> 6) * 68 + c] = fmaxf(fmaf(Y[i], sc[c], sh[c]), 0.f);
  }
  const int tr = t >> 4;
  const int tc4 = (t & 15) * 4;
  for (int hc = 0; hc < 2; ++hc) {
    __syncthreads();
    for (int i = t; i < 4096; i += 256)
      Bs[i] = W2[(i >> 6) * 128 + hc * 64 + (i & 63)];
    __syncthreads();
    float acc[4][4];
#pragma unroll
    for (int s = 0; s < 4; ++s)
#pragma unroll
      for (int j = 0; j < 4; ++j) acc[s][j] = B2[hc * 64 + tc4 + j];
    for (int k0 = 0; k0 < 64; k0 += 4) {
      float4 av[4];
#pragma unroll
      for (int s = 0; s < 4; ++s)
        av[s] = *reinterpret_cast<const float4*>(&As[(tr + 16 * s) * 68 + k0]);
#pragma unroll
      for (int kk = 0; kk < 4; ++kk) {
        const float4 bv = *reinterpret_cast<const float4*>(&Bs[(k0 + kk) * 64 + tc4]);
#pragma unroll
        for (int s = 0; s < 4; ++s) {
          const float a = (kk == 0) ? av[s].x : (kk == 1) ? av[s].y
                         : (kk == 2) ? av[s].z : av[s].w;
          acc[s][0] = fmaf(a, bv.x, acc[s][0]);
          acc[s][1] = fmaf(a, bv.y, acc[s][1]);
          acc[s][2] = fmaf(a, bv.z, acc[s][2]);
          acc[s][3] = fmaf(a, bv.w, acc[s][3]);
        }
      }
    }
#pragma unroll
    for (int s = 0; s < 4; ++s) {
      float4 o;
      o.x = acc[s][0]; o.y = acc[s][1]; o.z = acc[s][2]; o.w = acc[s][3];
      *reinterpret_cast<float4*>(&out[(tr + 16 * s) * 68 + tc4]) = o;
    }
    __syncthreads();
    if (t < 64) {
      float s = 0.f, q = 0.f;
      for (int r2 = 0; r2 < 64; ++r2) { const float v = out[r2 * 68 + t]; s += v; q += v * v; }
      psum[(size_t)(hc * 64 + t) * NBLK + blk] = s;
      psq[(size_t)(hc * 64 + t) * NBLK + blk] = q;
    }
    float* O = yout + (size_t)blk * 8192;
    for (int i = t; i < 4096; i += 256)
      O[(i >> 6) * 128 + hc * 64 + (i & 63)] = out[(i >> 6) * 68 + (i & 63)];
  }
}

__global__ __launch_bounds__(128) void l4s1_kernel(
    const float* __restrict__ y3pre, const float* __restrict__ sc3,
    const float* __restrict__ sh3, const float* __restrict__ sqsel,
    const float* __restrict__ sp, const float* __restrict__ W,
    const float* __restrict__ bia, float* __restrict__ y1) {
  __shared__ float sqs[64];
  __shared__ float row[132];
  const int blk = blockIdx.x;
  const int t = threadIdx.x;
  if (t < 64) sqs[t] = sqsel[(size_t)blk * 64 + t];
  __syncthreads();
  const float scv = sc3[t], shv = sh3[t];
  const float* Y = y3pre + (size_t)blk * 8192;
  float mx = -1e8f;
  for (int r = 0; r < 64; ++r) {
    const float act = fmaxf(fmaf(Y[r * 128 + t], scv, shv), 0.f);
    const float v = (sqs[r] <= 0.16f) ? act : -1e8f;
    mx = fmaxf(mx, v);
  }
  if (t < 3) row[t] = sp[(size_t)blk * 3 + t];
  row[3 + t] = mx;
  __syncthreads();
  float acc = bia[t];
  for (int cin = 0; cin < 131; ++cin) acc = fmaf(row[cin], W[(size_t)cin * 128 + t], acc);
  y1[(size_t)blk * 128 + t] = acc;
}

__global__ __launch_bounds__(256) void p_stats(const float* __restrict__ psum,
                                               const float* __restrict__ psq,
                                               float invN,
                                               const float* __restrict__ g,
                                               const float* __restrict__ be,
                                               float* __restrict__ sc,
                                               float* __restrict__ sh) {
  const int c = blockIdx.x;
  const int t = threadIdx.x;
  double s = 0.0, q = 0.0;
  for (int k = t; k < NBLK; k += 256) {
    s += (double)psum[(size_t)c * NBLK + k];
    q += (double)psq[(size_t)c * NBLK + k];
  }
  __shared__ double ss[256], qq[256];
  ss[t] = s;
  qq[t] = q;
  __syncthreads();
  for (int st = 128; st > 0; st >>= 1) {
    if (t < st) { ss[t] += ss[t + st]; qq[t] += qq[t + st]; }
    __syncthreads();
  }
  if (t == 0) {
    const double mean = ss[0] * (double)invN;
    double var = qq[0] * (double)invN - mean * mean;
    if (var < 0.0) var = 0.0;
    const float scl = (float)((double)g[c] / sqrt(var + 1e-5));
    sc[c] = scl;
    sh[c] = be[c] - (float)mean * scl;
  }
}

// ---------------------------------------------------------------- stage 1
__global__ __launch_bounds__(128) void s2_kernel(const float* __restrict__ y1,
                                                 const float* __restrict__ sc, const float* __restrict__ sh,
                                                 const float* __restrict__ W, const float* __restrict__ bia,
                                                 float* __restrict__ y2) {
  __shared__ float row[128];
  const int rowid = blockIdx.x;
  const int t = threadIdx.x;
  row[t] = fmaxf(fmaf(y1[(size_t)rowid * 128 + t], sc[t], sh[t]), 0.f);
  __syncthreads();
  float acc = bia[t];
  for (int cin = 0; cin < 128; ++cin) acc = fmaf(row[cin], W[(size_t)cin * 128 + t], acc);
  y2[(size_t)rowid * 128 + t] = acc;
}

__global__ __launch_bounds__(256) void s3_kernel(const float* __restrict__ y2,
                                                 const float* __restrict__ sc, const float* __restrict__ sh,
                                                 const float* __restrict__ W, const float* __restrict__ bia,
                                                 float* __restrict__ y3) {
  __shared__ float row[128];
  const int rowid = blockIdx.x;
  const int t = threadIdx.x;
  if (t < 128) row[t] = fmaxf(fmaf(y2[(size_t)rowid * 128 + t], sc[t], sh[t]), 0.f);
  __syncthreads();
  for (int h = 0; h < 2; ++h) {
    const int c = h * 256 + t;
    float acc = bia[c];
    for (int cin = 0; cin < 128; ++cin) acc = fmaf(row[cin], W[(size_t)cin * 512 + c], acc);
    y3[(size_t)rowid * 512 + c] = acc;
  }
}

__global__ __launch_bounds__(256) void s_stats(const float* __restrict__ y, int C, int rows,
                                               const float* __restrict__ g, const float* __restrict__ be,
                                               float* __restrict__ sc, float* __restrict__ sh) {
  const int c = blockIdx.x;
  const int t = threadIdx.x;
  double s = 0.0, q = 0.0;
  for (int r2 = t; r2 < rows; r2 += 256) {
    const double v = (double)y[(size_t)r2 * C + c];
    s += v;
    q += v * v;
  }
  __shared__ double ss[256], qq[256];
  ss[t] = s;
  qq[t] = q;
  __syncthreads();
  for (int st = 128; st > 0; st >>= 1) {
    if (t < st) { ss[t] += ss[t + st]; qq[t] += qq[t + st]; }
    __syncthreads();
  }
  if (t == 0) {
    const double mean = ss[0] / rows;
    double var = qq[0] / rows - mean * mean;
    if (var < 0.0) var = 0.0;
    const float scl = (float)((double)g[c] / sqrt(var + 1e-5));
    sc[c] = scl;
    sh[c] = be[c] - (float)mean * scl;
  }
}

__global__ __launch_bounds__(256) void s_stats_final(const float* __restrict__ y3,
                                                     const float* __restrict__ g,
                                                     const float* __restrict__ be,
                                                     float* __restrict__ out) {
  const int c = blockIdx.x;
  const int t = threadIdx.x;
  double s = 0.0, q = 0.0;
  for (int r2 = t; r2 < NBLK; r2 += 256) {
    const double v = (double)y3[(size_t)r2 * 512 + c];
    s += v;
    q += v * v;
  }
  __shared__ double ss[256], qq[256];
  __shared__ float sscl, sshv;
  ss[t] = s;
  qq[t] = q;
  __syncthreads();
  for (int st = 128; st > 0; st >>= 1) {
    if (t < st) { ss[t] += ss[t + st]; qq[t] += qq[t + st]; }
    __syncthreads();
  }
  if (t == 0) {
    const double mean = ss[0] / NBLK;
    double var = qq[0] / NBLK - mean * mean;
    if (var < 0.0) var = 0.0;
    const float scl = (float)((double)g[c] / sqrt(var + 1e-5));
    sscl = scl;
    sshv = be[c] - (float)mean * scl;
  }
  __syncthreads();
  const float scl = sscl, shv = sshv;
  float mx = -3.402823466e+38f;
  for (int k = 0; k < 8; ++k) {
    const int r = t * 8 + k;
    const float v = fmaxf(fmaf(y3[(size_t)r * 512 + c], scl, shv), 0.f);
    mx = fmaxf(mx, v);
  }
  __shared__ float pmax[256];
  pmax[t] = mx;
  __syncthreads();
  if (t < 16) {
    float m = -3.402823466e+38f;
    for (int j = 0; j < 16; ++j) m = fmaxf(m, pmax[t * 16 + j]);
    out[(size_t)t * 512 + c] = m;
  }
  if (c == 0 && t < 48) out[8192 + t] = 0.f;  // pos_out zeros
}

extern "C" void kernel_launch(void* const* d_in, const int* in_sizes, int n_in,
                              void* d_out, int out_size, void* d_ws, size_t ws_size,
                              hipStream_t stream) {
  const float* x    = (const float*)d_in[0];
  const float* pos  = (const float*)d_in[1];
  const float* W00  = (const float*)d_in[2];
  const float* b00  = (const float*)d_in[3];
  const float* g00  = (const float*)d_in[4];
  const float* be00 = (const float*)d_in[5];
  const float* W01  = (const float*)d_in[6];
  const float* b01  = (const float*)d_in[7];
  const float* g01  = (const float*)d_in[8];
  const float* be01 = (const float*)d_in[9];
  const float* W02  = (const float*)d_in[10];
  const float* b02  = (const float*)d_in[11];
  const float* g02  = (const float*)d_in[12];
  const float* be02 = (const float*)d_in[13];
  const float* W10  = (const float*)d_in[14];
  const float* b10  = (const float*)d_in[15];
  const float* g10  = (const float*)d_in[16];
  const float* be10 = (const float*)d_in[17];
  const float* W11  = (const float*)d_in[18];
  const float* b11  = (const float*)d_in[19];
  const float* g11  = (const float*)d_in[20];
  const float* be11 = (const float*)d_in[21];
  const float* W12  = (const float*)d_in[22];
  const float* b12  = (const float*)d_in[23];
  const float* g12  = (const float*)d_in[24];
  const float* be12 = (const float*)d_in[25];

  float* w = (float*)d_ws;
  float* sp    = w;                  // 6144
  float* gf0   = sp + 6144;          // 786432
  float* sqsel = gf0 + 786432;       // 131072
  float* x1    = sqsel + 131072;     // 262144 (unused)
  float* parts = x1 + 262144;        // 524288
  float* psum  = parts;
  float* psq   = parts + 128 * NBLK;
  float* st    = parts + 524288;     // 2048
  float* sc1 = st + 0,    *sh1 = st + 64;
  float* sc2 = st + 128,  *sh2 = st + 192;
  float* sc3 = st + 256,  *sh3 = st + 384;
  float* t1sc = st + 512, *t1sh = st + 640;
  float* t2sc = st + 768, *t2sh = st + 896;
  float* y1s = st + 2048;            // 262144
  float* y2s = y1s + 262144;         // 262144
  float* y3s = y2s + 262144;         // 1048576
  const size_t BASE = 3284992;
  float* y1pre = w + BASE;                       // 8388608
  float* y2pre = y1pre + 8388608;                // 8388608
  float* y3pre = y2pre + 8388608;                // 16777216
  int*   prog  = (int*)(y3pre + 16777216);       // 16 ints

  hipMemsetAsync(prog, 0, BATCH * sizeof(int), stream);
  {
    const float* a0 = pos;
    const float* a1 = x;
    float* a2 = sp;
    float* a3 = gf0;
    float* a4 = sqsel;
    int* a5 = prog;
    void* args[6] = {(void*)&a0, (void*)&a1, (void*)&a2,
                     (void*)&a3, (void*)&a4, (void*)&a5};
    hipLaunchCooperativeKernel((const void*)fk_kernel, dim3(256), dim3(1024),
                               args, DYN_BYTES, stream);
  }

  const float invN0 = 1.0f / (float)(NBLK * KNB);  // 1/131072
  l1_kernel<<<NBLK, 256, 0, stream>>>(gf0, W00, b00, psum, psq, y1pre);
  p_stats<<<64, 256, 0, stream>>>(psum, psq, invN0, g00, be00, sc1, sh1);
  l2_kernel<<<NBLK, 256, 0, stream>>>(y1pre, sc1, sh1, W01, b01, psum, psq, y2pre);
  p_stats<<<64, 256, 0, stream>>>(psum, psq, invN0, g01, be01, sc2, sh2);
  l3_kernel<<<NBLK, 256, 0, stream>>>(y2pre, sc2, sh2, W02, b02, psum, psq, y3pre);
  p_stats<<<128, 256, 0, stream>>>(psum, psq, invN0, g02, be02, sc3, sh3);
  l4s1_kernel<<<NBLK, 128, 0, stream>>>(y3pre, sc3, sh3, sqsel, sp, W10, b10, y1s);

  s_stats<<<128, 256, 0, stream>>>(y1s, 128, NBLK, g10, be10, t1sc, t1sh);
  s2_kernel<<<NBLK, 128, 0, stream>>>(y1s, t1sc, t1sh, W11, b11, y2s);
  s_stats<<<128, 256, 0, stream>>>(y2s, 128, NBLK, g11, be11, t2sc, t2sh);
  s3_kernel<<<NBLK, 256, 0, stream>>>(y2s, t2sc, t2sh, W12, b12, y3s);
  s_stats_final<<<512, 256, 0, stream>>>(y3s, g12, be12, (float*)d_out);
}

// Round 15
// 529.415 us; speedup vs baseline: 1.1563x; 1.1563x over previous
//
#include <hip/hip_runtime.h>
#include <cstdint>
#include <cstddef>

#define NPTS 8192
#define BATCH 16
#define MS 128
#define KNB 64
#define NBLK (BATCH * MS)   // 2048
#define KNNBLK 240          // knn-role blocks in the fused cooperative grid
#define NQUAD 512           // 2048 samples / 4 per quad
#define PROGSTRIDE 32       // ints per progress slot (128B -> no line sharing)
// dynamic LDS partition (bytes)
#define SQV_Q 8224                      // floats per quarter (swizzle pad)
#define WL_OFF (4 * SQV_Q * 4)          // 131584
#define SELK_OFF (WL_OFF + 8192)        // 139776
#define DYN_BYTES (SELK_OFF + 2048)     // 141824

// ---------------- DPP wave reductions (VALU-speed, no LDS crossbar) ----------
__device__ __forceinline__ float dpp_wave_max_f32(float v) {
  v = fmaxf(v, __int_as_float(__builtin_amdgcn_update_dpp((int)0xff800000, __float_as_int(v), 0x111, 0xf, 0xf, false)));
  v = fmaxf(v, __int_as_float(__builtin_amdgcn_update_dpp((int)0xff800000, __float_as_int(v), 0x112, 0xf, 0xf, false)));
  v = fmaxf(v, __int_as_float(__builtin_amdgcn_update_dpp((int)0xff800000, __float_as_int(v), 0x114, 0xf, 0xf, false)));
  v = fmaxf(v, __int_as_float(__builtin_amdgcn_update_dpp((int)0xff800000, __float_as_int(v), 0x118, 0xf, 0xf, false)));
  v = fmaxf(v, __int_as_float(__builtin_amdgcn_update_dpp((int)0xff800000, __float_as_int(v), 0x142, 0xa, 0xf, false)));
  v = fmaxf(v, __int_as_float(__builtin_amdgcn_update_dpp((int)0xff800000, __float_as_int(v), 0x143, 0xc, 0xf, false)));
  return v;  // lane 63
}

__device__ __forceinline__ float dpp_wave_min_f32(float v) {
  v = fminf(v, __int_as_float(__builtin_amdgcn_update_dpp(0x7f800000, __float_as_int(v), 0x111, 0xf, 0xf, false)));
  v = fminf(v, __int_as_float(__builtin_amdgcn_update_dpp(0x7f800000, __float_as_int(v), 0x112, 0xf, 0xf, false)));
  v = fminf(v, __int_as_float(__builtin_amdgcn_update_dpp(0x7f800000, __float_as_int(v), 0x114, 0xf, 0xf, false)));
  v = fminf(v, __int_as_float(__builtin_amdgcn_update_dpp(0x7f800000, __float_as_int(v), 0x118, 0xf, 0xf, false)));
  v = fminf(v, __int_as_float(__builtin_amdgcn_update_dpp(0x7f800000, __float_as_int(v), 0x142, 0xa, 0xf, false)));
  v = fminf(v, __int_as_float(__builtin_amdgcn_update_dpp(0x7f800000, __float_as_int(v), 0x143, 0xc, 0xf, false)));
  return v;  // lane 63
}

__device__ __forceinline__ unsigned dpp_wave_min_u32(unsigned v) {
  unsigned o;
  o = (unsigned)__builtin_amdgcn_update_dpp((int)0xffffffffu, (int)v, 0x111, 0xf, 0xf, false); v = (o < v) ? o : v;
  o = (unsigned)__builtin_amdgcn_update_dpp((int)0xffffffffu, (int)v, 0x112, 0xf, 0xf, false); v = (o < v) ? o : v;
  o = (unsigned)__builtin_amdgcn_update_dpp((int)0xffffffffu, (int)v, 0x114, 0xf, 0xf, false); v = (o < v) ? o : v;
  o = (unsigned)__builtin_amdgcn_update_dpp((int)0xffffffffu, (int)v, 0x118, 0xf, 0xf, false); v = (o < v) ? o : v;
  o = (unsigned)__builtin_amdgcn_update_dpp((int)0xffffffffu, (int)v, 0x142, 0xa, 0xf, false); v = (o < v) ? o : v;
  o = (unsigned)__builtin_amdgcn_update_dpp((int)0xffffffffu, (int)v, 0x143, 0xc, 0xf, false); v = (o < v) ? o : v;
  return v;  // lane 63
}

__device__ __forceinline__ float dpp_row_max_f32(float v) {  // lane 15 of each row
  v = fmaxf(v, __int_as_float(__builtin_amdgcn_update_dpp((int)0xff800000, __float_as_int(v), 0x111, 0xf, 0xf, false)));
  v = fmaxf(v, __int_as_float(__builtin_amdgcn_update_dpp((int)0xff800000, __float_as_int(v), 0x112, 0xf, 0xf, false)));
  v = fmaxf(v, __int_as_float(__builtin_amdgcn_update_dpp((int)0xff800000, __float_as_int(v), 0x114, 0xf, 0xf, false)));
  v = fmaxf(v, __int_as_float(__builtin_amdgcn_update_dpp((int)0xff800000, __float_as_int(v), 0x118, 0xf, 0xf, false)));
  return v;
}

__device__ __forceinline__ unsigned dpp_row_min_u32(unsigned v) {  // lane 15 of each row
  unsigned o;
  o = (unsigned)__builtin_amdgcn_update_dpp((int)0xffffffffu, (int)v, 0x111, 0xf, 0xf, false); v = (o < v) ? o : v;
  o = (unsigned)__builtin_amdgcn_update_dpp((int)0xffffffffu, (int)v, 0x112, 0xf, 0xf, false); v = (o < v) ? o : v;
  o = (unsigned)__builtin_amdgcn_update_dpp((int)0xffffffffu, (int)v, 0x114, 0xf, 0xf, false); v = (o < v) ? o : v;
  o = (unsigned)__builtin_amdgcn_update_dpp((int)0xffffffffu, (int)v, 0x118, 0xf, 0xf, false); v = (o < v) ? o : v;
  return v;
}

// ======================= fused FPS + kNN (cooperative) =======================
// Round-14 logic (verified correct) + contention fixes: prog padded to 128B
// per entry, spin polls backed off with s_sleep (~0.85us) -> coherence traffic
// drops from ~100GB to ~nothing; fps writer no longer stalls on line ping-pong.
#define FPS_STEP(J)                                                        \
  {                                                                        \
    const float4 p = pts4[J * 1024 + t];                                   \
    const float dx = p.x - lx;                                             \
    const float dy = p.y - ly;                                             \
    const float dz = p.z - lz;                                             \
    const float d = dx * dx + dy * dy + dz * dz;                           \
    md##J = fminf(md##J, d);                                               \
  }

#define FPS_RESCAN(J)                                                      \
  if (md##J == wv) best = (unsigned)(J * 1024 + t);

__global__ __launch_bounds__(1024, 4) void fk_kernel(const float* __restrict__ pos,
                                                     const float* __restrict__ xf,
                                                     float* __restrict__ sp,
                                                     float* __restrict__ gf0,
                                                     float* __restrict__ sqsel,
                                                     int* __restrict__ prog) {
#pragma clang fp contract(off)
  extern __shared__ char dynls[];
  const int blk = blockIdx.x;
  const int tid = threadIdx.x;
  if (blk < BATCH) {
    // ------------------------------ fps role ------------------------------
    float4* pts4 = reinterpret_cast<float4*>(dynls);
    __shared__ float wval[2][16];
    __shared__ unsigned widx[2][16];
    const int b = blk;
    const float* P = pos + (size_t)b * NPTS * 3;
    const int t = tid;
    const int wave = t >> 6;
    const int lane = t & 63;
    float md0 = 1e10f, md1 = 1e10f, md2 = 1e10f, md3 = 1e10f;
    float md4 = 1e10f, md5 = 1e10f, md6 = 1e10f, md7 = 1e10f;
    for (int i = t; i < NPTS; i += 1024)
      pts4[i] = make_float4(P[i * 3 + 0], P[i * 3 + 1], P[i * 3 + 2], 0.f);
    float lx = P[0], ly = P[1], lz = P[2];
    __syncthreads();
    for (int it = 0; it < MS; ++it) {
      if (t == 0) {
        sp[((size_t)b * MS + it) * 3 + 0] = lx;
        sp[((size_t)b * MS + it) * 3 + 1] = ly;
        sp[((size_t)b * MS + it) * 3 + 2] = lz;
        __hip_atomic_store(&prog[b * PROGSTRIDE], it + 1, __ATOMIC_RELEASE,
                           __HIP_MEMORY_SCOPE_AGENT);
      }
      FPS_STEP(0) FPS_STEP(1) FPS_STEP(2) FPS_STEP(3)
      FPS_STEP(4) FPS_STEP(5) FPS_STEP(6) FPS_STEP(7)
      const float m01 = fmaxf(md0, md1), m23 = fmaxf(md2, md3);
      const float m45 = fmaxf(md4, md5), m67 = fmaxf(md6, md7);
      const float bv = fmaxf(fmaxf(m01, m23), fmaxf(m45, m67));
      const float wv = __int_as_float(
          __builtin_amdgcn_readlane(__float_as_int(dpp_wave_max_f32(bv)), 63));
      unsigned best = 0xffffffffu;
      if (bv == wv) {
        FPS_RESCAN(7) FPS_RESCAN(6) FPS_RESCAN(5) FPS_RESCAN(4)
        FPS_RESCAN(3) FPS_RESCAN(2) FPS_RESCAN(1) FPS_RESCAN(0)
      }
      const unsigned wi =
          (unsigned)__builtin_amdgcn_readlane((int)dpp_wave_min_u32(best), 63);
      const int par = it & 1;
      if (lane == 0) { wval[par][wave] = wv; widx[par][wave] = wi; }
      __syncthreads();
      const float a = wval[par][lane & 15];
      const float Mx = __int_as_float(
          __builtin_amdgcn_readlane(__float_as_int(dpp_row_max_f32(a)), 15));
      const unsigned c2 = (a == Mx) ? widx[par][lane & 15] : 0xffffffffu;
      const unsigned idx =
          (unsigned)__builtin_amdgcn_readlane((int)dpp_row_min_u32(c2), 15);
      const float4 c = pts4[idx];
      lx = c.x; ly = c.y; lz = c.z;
    }
  } else {
    // ------------------------------ knn role ------------------------------
    const int k = blk - BATCH;  // 0..239
    const int q = tid >> 8;     // quarter 0..3
    const int t = tid & 255;    // thread-in-quarter
    const int wave = t >> 6;    // wave-in-quarter 0..3
    const int lane = tid & 63;  // HW lane
    float* sqv = reinterpret_cast<float*>(dynls) + q * SQV_Q;
    unsigned long long* wl =
        reinterpret_cast<unsigned long long*>(dynls + WL_OFF) + (size_t)q * 256;
    unsigned long long* selk =
        reinterpret_cast<unsigned long long*>(dynls + SELK_OFF) + (size_t)q * 64;
    for (int Q = k; Q < NQUAD; Q += KNNBLK) {
      const int m = Q >> 2;
      const int g = Q & 3;
      const int batch = 4 * g + q;
      if (tid == 0) {
        for (int bb = 0; bb < 4; ++bb) {
          while (__hip_atomic_load(&prog[(4 * g + bb) * PROGSTRIDE],
                                   __ATOMIC_ACQUIRE,
                                   __HIP_MEMORY_SCOPE_AGENT) <= m)
            __builtin_amdgcn_s_sleep(32);  // ~2k cycles between polls
        }
      }
      __syncthreads();
      (void)__hip_atomic_load(&prog[batch * PROGSTRIDE], __ATOMIC_ACQUIRE,
                              __HIP_MEMORY_SCOPE_AGENT);  // visibility edge
      const int bm = batch * MS + m;
      const float* P = pos + (size_t)batch * NPTS * 3;
      const float sx = sp[bm * 3 + 0], sy = sp[bm * 3 + 1], sz = sp[bm * 3 + 2];
      const float nsp = sx * sx + sy * sy + sz * sz;
      float cv;
      unsigned ci;
      {
        unsigned long long k0 = ~0ULL;
        for (int j = 0; j < 32; ++j) {
          const int i = j * 256 + t;
          const float qx = P[i * 3 + 0], qy = P[i * 3 + 1], qz = P[i * 3 + 2];
          const float npos = qx * qx + qy * qy + qz * qz;
          const float dt = sx * qx + sy * qy + sz * qz;
          float sq = (nsp + npos) - 2.0f * dt;  // ||a||^2+||b||^2-2ab order
          sq = fmaxf(sq, 0.0f);
          sqv[i + j] = sq;  // swizzle: i>>8 == j
          const unsigned long long key =
              ((unsigned long long)__float_as_uint(sq) << 32) | (unsigned)i;
          if (key < k0) k0 = key;
        }
        cv = __uint_as_float((unsigned)(k0 >> 32));
        ci = (unsigned)k0;
      }
      __syncthreads();
      unsigned cmask = 0u;
      for (int round = 0; round < KNB; ++round) {
        const float wv = __int_as_float(
            __builtin_amdgcn_readlane(__float_as_int(dpp_wave_min_f32(cv)), 63));
        const unsigned sel = (cv == wv) ? ci : 0xffffffffu;
        const unsigned wi =
            (unsigned)__builtin_amdgcn_readlane((int)dpp_wave_min_u32(sel), 63);
        if (lane == 0)
          wl[wave * 64 + round] =
              ((unsigned long long)__float_as_uint(wv) << 32) | wi;
        const int col = (int)(wi & 255u);
        const int ownerLane = col & 63;
        const unsigned jsel = wi >> 8;
        if (lane == ownerLane) cmask |= (1u << jsel);
        const unsigned omask =
            (unsigned)__builtin_amdgcn_readlane((int)cmask, ownerLane);
        float v = __uint_as_float(0x7f800000u);
        unsigned ii = 0xffffffffu;
        if (lane < 32 && !((omask >> lane) & 1u)) {
          const int i = lane * 256 + col;
          v = sqv[i + lane];
          ii = (unsigned)i;
        }
        const float mv = __int_as_float(
            __builtin_amdgcn_readlane(__float_as_int(dpp_wave_min_f32(v)), 63));
        const unsigned s2 = (v == mv) ? ii : 0xffffffffu;
        const unsigned mi =
            (unsigned)__builtin_amdgcn_readlane((int)dpp_wave_min_u32(s2), 63);
        if (lane == ownerLane) { cv = mv; ci = mi; }
      }
      __syncthreads();
      {
        const int w = wave, r = lane;
        const unsigned long long e = wl[w * 64 + r];
        int rank = r;
#pragma unroll
        for (int w2 = 0; w2 < 4; ++w2) {
          if (w2 == w) continue;
          int lo = 0;
#pragma unroll
          for (int step = 32; step > 0; step >>= 1)
            if (lo + step <= KNB && wl[w2 * 64 + lo + step - 1] < e) lo += step;
          rank += lo;
        }
        if (rank < KNB) selk[rank] = e;
      }
      __syncthreads();
      if (t < KNB) {
        const unsigned long long e = selk[t];
        const int i = (int)(e & 0xffffffffu);
        const float* X = xf + (size_t)batch * NPTS * 3;
        const size_t base = ((size_t)bm * KNB + t) * 6;
        gf0[base + 0] = P[i * 3 + 0] - sx;
        gf0[base + 1] = P[i * 3 + 1] - sy;
        gf0[base + 2] = P[i * 3 + 2] - sz;
        gf0[base + 3] = X[i * 3 + 0];
        gf0[base + 4] = X[i * 3 + 1];
        gf0[base + 5] = X[i * 3 + 2];
        sqsel[(size_t)bm * KNB + t] = __uint_as_float((unsigned)(e >> 32));
      }
      __syncthreads();  // before restaging sqv next quad
    }
  }
}

// ================================================================ chain
__global__ __launch_bounds__(256) void l1_kernel(
    const float* __restrict__ gf0, const float* __restrict__ W0,
    const float* __restrict__ B0,
    float* __restrict__ psum, float* __restrict__ psq,
    float* __restrict__ y1pre) {
  __shared__ float in6[64 * 8];
  __shared__ float wbuf[384];
  __shared__ float out[64 * 65];
  const int blk = blockIdx.x;
  const int t = threadIdx.x;
  const float* G = gf0 + (size_t)blk * 384;
  for (int i = t; i < 384; i += 256) in6[(i / 6) * 8 + (i % 6)] = G[i];
  for (int i = t; i < 384; i += 256) wbuf[i] = W0[i];
  __syncthreads();
  const int r = t >> 2;
  const int c0 = (t & 3) * 16;
  float acc[16];
#pragma unroll
  for (int j = 0; j < 16; ++j) acc[j] = B0[c0 + j];
  for (int cin = 0; cin < 6; ++cin) {
    const float a = in6[r * 8 + cin];
#pragma unroll
    for (int j = 0; j < 16; ++j) acc[j] = fmaf(a, wbuf[cin * 64 + c0 + j], acc[j]);
  }
#pragma unroll
  for (int j = 0; j < 16; ++j) out[r * 65 + c0 + j] = acc[j];
  __syncthreads();
  if (t < 64) {
    float s = 0.f, q = 0.f;
    for (int r2 = 0; r2 < 64; ++r2) { const float v = out[r2 * 65 + t]; s += v; q += v * v; }
    psum[(size_t)t * NBLK + blk] = s;
    psq[(size_t)t * NBLK + blk] = q;
  }
  float* Y = y1pre + (size_t)blk * 4096;
  for (int i = t; i < 4096; i += 256) Y[i] = out[(i >> 6) * 65 + (i & 63)];
}

__global__ __launch_bounds__(256) void l2_kernel(
    const float* __restrict__ ypre, const float* __restrict__ sc,
    const float* __restrict__ sh, const float* __restrict__ W1,
    const float* __restrict__ B1,
    float* __restrict__ psum, float* __restrict__ psq,
    float* __restrict__ yout) {
  __shared__ float As[64 * 68];
  __shared__ float Bs[64 * 64];
  __shared__ float out[64 * 68];
  const int blk = blockIdx.x;
  const int t = threadIdx.x;
  const float* Y = ypre + (size_t)blk * 4096;
  for (int i = t; i < 4096; i += 256) {
    const int c = i & 63;
    As[(i >> 6) * 68 + c] = fmaxf(fmaf(Y[i], sc[c], sh[c]), 0.f);
  }
  for (int i = t; i < 4096; i += 256) Bs[i] = W1[i];
  __syncthreads();
  const int tr = t >> 4;
  const int tc4 = (t & 15) * 4;
  float acc[4][4];
#pragma unroll
  for (int s = 0; s < 4; ++s)
#pragma unroll
    for (int j = 0; j < 4; ++j) acc[s][j] = B1[tc4 + j];
  for (int k0 = 0; k0 < 64; k0 += 4) {
    float4 av[4];
#pragma unroll
    for (int s = 0; s < 4; ++s)
      av[s] = *reinterpret_cast<const float4*>(&As[(tr + 16 * s) * 68 + k0]);
#pragma unroll
    for (int kk = 0; kk < 4; ++kk) {
      const float4 bv = *reinterpret_cast<const float4*>(&Bs[(k0 + kk) * 64 + tc4]);
#pragma unroll
      for (int s = 0; s < 4; ++s) {
        const float a = (kk == 0) ? av[s].x : (kk == 1) ? av[s].y
                       : (kk == 2) ? av[s].z : av[s].w;
        acc[s][0] = fmaf(a, bv.x, acc[s][0]);
        acc[s][1] = fmaf(a, bv.y, acc[s][1]);
        acc[s][2] = fmaf(a, bv.z, acc[s][2]);
        acc[s][3] = fmaf(a, bv.w, acc[s][3]);
      }
    }
  }
#pragma unroll
  for (int s = 0; s < 4; ++s) {
    float4 o;
    o.x = acc[s][0]; o.y = acc[s][1]; o.z = acc[s][2]; o.w = acc[s][3];
    *reinterpret_cast<float4*>(&out[(tr + 16 * s) * 68 + tc4]) = o;
  }
  __syncthreads();
  if (t < 64) {
    float s = 0.f, q = 0.f;
    for (int r2 = 0; r2 < 64; ++r2) { const float v = out[r2 * 68 + t]; s += v; q += v * v; }
    psum[(size_t)t * NBLK + blk] = s;
    psq[(size_t)t * NBLK + blk] = q;
  }
  float* O = yout + (size_t)blk * 4096;
  for (int i = t; i < 4096; i += 256) O[i] = out[(i >> 6) * 68 + (i & 63)];
}

__global__ __launch_bounds__(256) void l3_kernel(
    const float* __restrict__ ypre, const float* __restrict__ sc,
    const float* __restrict__ sh, const float* __restrict__ W2,
    const float* __restrict__ B2,
    float* __restrict__ psum, float* __restrict__ psq,
    float* __restrict__ yout) {
  __shared__ float As[64 * 68];
  __shared__ float Bs[64 * 64];
  __shared__ float out[64 * 68];
  const int blk = blockIdx.x;
  const int t = threadIdx.x;
  const float* Y = ypre + (size_t)blk * 4096;
  for (int i = t; i < 4096; i += 256) {
    const int c = i & 63;
    As[(i >> 6) * 68 + c] = fmaxf(fmaf(Y[i], sc[c], sh[c]), 0.f);
  }
  const int tr = t >> 4;
  const int tc4 = (t & 15) * 4;
  for (int hc = 0; hc < 2; ++hc) {
    __syncthreads();
    for (int i = t; i < 4096; i += 256)
      Bs[i] = W2[(i >> 6) * 128 + hc * 64 + (i & 63)];
    __syncthreads();
    float acc[4][4];
#pragma unroll
    for (int s = 0; s < 4; ++s)
#pragma unroll
      for (int j = 0; j < 4; ++j) acc[s][j] = B2[hc * 64 + tc4 + j];
    for (int k0 = 0; k0 < 64; k0 += 4) {
      float4 av[4];
#pragma unroll
      for (int s = 0; s < 4; ++s)
        av[s] = *reinterpret_cast<const float4*>(&As[(tr + 16 * s) * 68 + k0]);
#pragma unroll
      for (int kk = 0; kk < 4; ++kk) {
        const float4 bv = *reinterpret_cast<const float4*>(&Bs[(k0 + kk) * 64 + tc4]);
#pragma unroll
        for (int s = 0; s < 4; ++s) {
          const float a = (kk == 0) ? av[s].x : (kk == 1) ? av[s].y
                         : (kk == 2) ? av[s].z : av[s].w;
          acc[s][0] = fmaf(a, bv.x, acc[s][0]);
          acc[s][1] = fmaf(a, bv.y, acc[s][1]);
          acc[s][2] = fmaf(a, bv.z, acc[s][2]);
          acc[s][3] = fmaf(a, bv.w, acc[s][3]);
        }
      }
    }
#pragma unroll
    for (int s = 0; s < 4; ++s) {
      float4 o;
      o.x = acc[s][0]; o.y = acc[s][1]; o.z = acc[s][2]; o.w = acc[s][3];
      *reinterpret_cast<float4*>(&out[(tr + 16 * s) * 68 + tc4]) = o;
    }
    __syncthreads();
    if (t < 64) {
      float s = 0.f, q = 0.f;
      for (int r2 = 0; r2 < 64; ++r2) { const float v = out[r2 * 68 + t]; s += v; q += v * v; }
      psum[(size_t)(hc * 64 + t) * NBLK + blk] = s;
      psq[(size_t)(hc * 64 + t) * NBLK + blk] = q;
    }
    float* O = yout + (size_t)blk * 8192;
    for (int i = t; i < 4096; i += 256)
      O[(i >> 6) * 128 + hc * 64 + (i & 63)] = out[(i >> 6) * 68 + (i & 63)];
  }
}

__global__ __launch_bounds__(128) void l4s1_kernel(
    const float* __restrict__ y3pre, const float* __restrict__ sc3,
    const float* __restrict__ sh3, const float* __restrict__ sqsel,
    const float* __restrict__ sp, const float* __restrict__ W,
    const float* __restrict__ bia, float* __restrict__ y1) {
  __shared__ float sqs[64];
  __shared__ float row[132];
  const int blk = blockIdx.x;
  const int t = threadIdx.x;
  if (t < 64) sqs[t] = sqsel[(size_t)blk * 64 + t];
  __syncthreads();
  const float scv = sc3[t], shv = sh3[t];
  const float* Y = y3pre + (size_t)blk * 8192;
  float mx = -1e8f;
  for (int r = 0; r < 64; ++r) {
    const float act = fmaxf(fmaf(Y[r * 128 + t], scv, shv), 0.f);
    const float v = (sqs[r] <= 0.16f) ? act : -1e8f;
    mx = fmaxf(mx, v);
  }
  if (t < 3) row[t] = sp[(size_t)blk * 3 + t];
  row[3 + t] = mx;
  __syncthreads();
  float acc = bia[t];
  for (int cin = 0; cin < 131; ++cin) acc = fmaf(row[cin], W[(size_t)cin * 128 + t], acc);
  y1[(size_t)blk * 128 + t] = acc;
}

__global__ __launch_bounds__(256) void p_stats(const float* __restrict__ psum,
                                               const float* __restrict__ psq,
                                               float invN,
                                               const float* __restrict__ g,
                                               const float* __restrict__ be,
                                               float* __restrict__ sc,
                                               float* __restrict__ sh) {
  const int c = blockIdx.x;
  const int t = threadIdx.x;
  double s = 0.0, q = 0.0;
  for (int k = t; k < NBLK; k += 256) {
    s += (double)psum[(size_t)c * NBLK + k];
    q += (double)psq[(size_t)c * NBLK + k];
  }
  __shared__ double ss[256], qq[256];
  ss[t] = s;
  qq[t] = q;
  __syncthreads();
  for (int st = 128; st > 0; st >>= 1) {
    if (t < st) { ss[t] += ss[t + st]; qq[t] += qq[t + st]; }
    __syncthreads();
  }
  if (t == 0) {
    const double mean = ss[0] * (double)invN;
    double var = qq[0] * (double)invN - mean * mean;
    if (var < 0.0) var = 0.0;
    const float scl = (float)((double)g[c] / sqrt(var + 1e-5));
    sc[c] = scl;
    sh[c] = be[c] - (float)mean * scl;
  }
}

// ---------------------------------------------------------------- stage 1
__global__ __launch_bounds__(128) void s2_kernel(const float* __restrict__ y1,
                                                 const float* __restrict__ sc, const float* __restrict__ sh,
                                                 const float* __restrict__ W, const float* __restrict__ bia,
                                                 float* __restrict__ y2) {
  __shared__ float row[128];
  const int rowid = blockIdx.x;
  const int t = threadIdx.x;
  row[t] = fmaxf(fmaf(y1[(size_t)rowid * 128 + t], sc[t], sh[t]), 0.f);
  __syncthreads();
  float acc = bia[t];
  for (int cin = 0; cin < 128; ++cin) acc = fmaf(row[cin], W[(size_t)cin * 128 + t], acc);
  y2[(size_t)rowid * 128 + t] = acc;
}

__global__ __launch_bounds__(256) void s3_kernel(const float* __restrict__ y2,
                                                 const float* __restrict__ sc, const float* __restrict__ sh,
                                                 const float* __restrict__ W, const float* __restrict__ bia,
                                                 float* __restrict__ y3) {
  __shared__ float row[128];
  const int rowid = blockIdx.x;
  const int t = threadIdx.x;
  if (t < 128) row[t] = fmaxf(fmaf(y2[(size_t)rowid * 128 + t], sc[t], sh[t]), 0.f);
  __syncthreads();
  for (int h = 0; h < 2; ++h) {
    const int c = h * 256 + t;
    float acc = bia[c];
    for (int cin = 0; cin < 128; ++cin) acc = fmaf(row[cin], W[(size_t)cin * 512 + c], acc);
    y3[(size_t)rowid * 512 + c] = acc;
  }
}

__global__ __launch_bounds__(256) void s_stats(const float* __restrict__ y, int C, int rows,
                                               const float* __restrict__ g, const float* __restrict__ be,
                                               float* __restrict__ sc, float* __restrict__ sh) {
  const int c = blockIdx.x;
  const int t = threadIdx.x;
  double s = 0.0, q = 0.0;
  for (int r2 = t; r2 < rows; r2 += 256) {
    const double v = (double)y[(size_t)r2 * C + c];
    s += v;
    q += v * v;
  }
  __shared__ double ss[256], qq[256];
  ss[t] = s;
  qq[t] = q;
  __syncthreads();
  for (int st = 128; st > 0; st >>= 1) {
    if (t < st) { ss[t] += ss[t + st]; qq[t] += qq[t + st]; }
    __syncthreads();
  }
  if (t == 0) {
    const double mean = ss[0] / rows;
    double var = qq[0] / rows - mean * mean;
    if (var < 0.0) var = 0.0;
    const float scl = (float)((double)g[c] / sqrt(var + 1e-5));
    sc[c] = scl;
    sh[c] = be[c] - (float)mean * scl;
  }
}

__global__ __launch_bounds__(256) void s_stats_final(const float* __restrict__ y3,
                                                     const float* __restrict__ g,
                                                     const float* __restrict__ be,
                                                     float* __restrict__ out) {
  const int c = blockIdx.x;
  const int t = threadIdx.x;
  double s = 0.0, q = 0.0;
  for (int r2 = t; r2 < NBLK; r2 += 256) {
    const double v = (double)y3[(size_t)r2 * 512 + c];
    s += v;
    q += v * v;
  }
  __shared__ double ss[256], qq[256];
  __shared__ float sscl, sshv;
  ss[t] = s;
  qq[t] = q;
  __syncthreads();
  for (int st = 128; st > 0; st >>= 1) {
    if (t < st) { ss[t] += ss[t + st]; qq[t] += qq[t + st]; }
    __syncthreads();
  }
  if (t == 0) {
    const double mean = ss[0] / NBLK;
    double var = qq[0] / NBLK - mean * mean;
    if (var < 0.0) var = 0.0;
    const float scl = (float)((double)g[c] / sqrt(var + 1e-5));
    sscl = scl;
    sshv = be[c] - (float)mean * scl;
  }
  __syncthreads();
  const float scl = sscl, shv = sshv;
  float mx = -3.402823466e+38f;
  for (int k = 0; k < 8; ++k) {
    const int r = t * 8 + k;
    const float v = fmaxf(fmaf(y3[(size_t)r * 512 + c], scl, shv), 0.f);
    mx = fmaxf(mx, v);
  }
  __shared__ float pmax[256];
  pmax[t] = mx;
  __syncthreads();
  if (t < 16) {
    float m = -3.402823466e+38f;
    for (int j = 0; j < 16; ++j) m = fmaxf(m, pmax[t * 16 + j]);
    out[(size_t)t * 512 + c] = m;
  }
  if (c == 0 && t < 48) out[8192 + t] = 0.f;  // pos_out zeros
}

extern "C" void kernel_launch(void* const* d_in, const int* in_sizes, int n_in,
                              void* d_out, int out_size, void* d_ws, size_t ws_size,
                              hipStream_t stream) {
  const float* x    = (const float*)d_in[0];
  const float* pos  = (const float*)d_in[1];
  const float* W00  = (const float*)d_in[2];
  const float* b00  = (const float*)d_in[3];
  const float* g00  = (const float*)d_in[4];
  const float* be00 = (const float*)d_in[5];
  const float* W01  = (const float*)d_in[6];
  const float* b01  = (const float*)d_in[7];
  const float* g01  = (const float*)d_in[8];
  const float* be01 = (const float*)d_in[9];
  const float* W02  = (const float*)d_in[10];
  const float* b02  = (const float*)d_in[11];
  const float* g02  = (const float*)d_in[12];
  const float* be02 = (const float*)d_in[13];
  const float* W10  = (const float*)d_in[14];
  const float* b10  = (const float*)d_in[15];
  const float* g10  = (const float*)d_in[16];
  const float* be10 = (const float*)d_in[17];
  const float* W11  = (const float*)d_in[18];
  const float* b11  = (const float*)d_in[19];
  const float* g11  = (const float*)d_in[20];
  const float* be11 = (const float*)d_in[21];
  const float* W12  = (const float*)d_in[22];
  const float* b12  = (const float*)d_in[23];
  const float* g12  = (const float*)d_in[24];
  const float* be12 = (const float*)d_in[25];

  float* w = (float*)d_ws;
  float* sp    = w;                  // 6144
  float* gf0   = sp + 6144;          // 786432
  float* sqsel = gf0 + 786432;       // 131072
  float* x1    = sqsel + 131072;     // 262144 (unused)
  float* parts = x1 + 262144;        // 524288
  float* psum  = parts;
  float* psq   = parts + 128 * NBLK;
  float* st    = parts + 524288;     // 2048
  float* sc1 = st + 0,    *sh1 = st + 64;
  float* sc2 = st + 128,  *sh2 = st + 192;
  float* sc3 = st + 256,  *sh3 = st + 384;
  float* t1sc = st + 512, *t1sh = st + 640;
  float* t2sc = st + 768, *t2sh = st + 896;
  float* y1s = st + 2048;            // 262144
  float* y2s = y1s + 262144;         // 262144
  float* y3s = y2s + 262144;         // 1048576
  const size_t BASE = 3284992;
  float* y1pre = w + BASE;                       // 8388608
  float* y2pre = y1pre + 8388608;                // 8388608
  float* y3pre = y2pre + 8388608;                // 16777216
  int*   prog  = (int*)(y3pre + 16777216);       // 16 * PROGSTRIDE ints

  hipMemsetAsync(prog, 0, BATCH * PROGSTRIDE * sizeof(int), stream);
  {
    const float* a0 = pos;
    const float* a1 = x;
    float* a2 = sp;
    float* a3 = gf0;
    float* a4 = sqsel;
    int* a5 = prog;
    void* args[6] = {(void*)&a0, (void*)&a1, (void*)&a2,
                     (void*)&a3, (void*)&a4, (void*)&a5};
    hipLaunchCooperativeKernel((const void*)fk_kernel, dim3(256), dim3(1024),
                               args, DYN_BYTES, stream);
  }

  const float invN0 = 1.0f / (float)(NBLK * KNB);  // 1/131072
  l1_kernel<<<NBLK, 256, 0, stream>>>(gf0, W00, b00, psum, psq, y1pre);
  p_stats<<<64, 256, 0, stream>>>(psum, psq, invN0, g00, be00, sc1, sh1);
  l2_kernel<<<NBLK, 256, 0, stream>>>(y1pre, sc1, sh1, W01, b01, psum, psq, y2pre);
  p_stats<<<64, 256, 0, stream>>>(psum, psq, invN0, g01, be01, sc2, sh2);
  l3_kernel<<<NBLK, 256, 0, stream>>>(y2pre, sc2, sh2, W02, b02, psum, psq, y3pre);
  p_stats<<<128, 256, 0, stream>>>(psum, psq, invN0, g02, be02, sc3, sh3);
  l4s1_kernel<<<NBLK, 128, 0, stream>>>(y3pre, sc3, sh3, sqsel, sp, W10, b10, y1s);

  s_stats<<<128, 256, 0, stream>>>(y1s, 128, NBLK, g10, be10, t1sc, t1sh);
  s2_kernel<<<NBLK, 128, 0, stream>>>(y1s, t1sc, t1sh, W11, b11, y2s);
  s_stats<<<128, 256, 0, stream>>>(y2s, 128, NBLK, g11, be11, t2sc, t2sh);
  s3_kernel<<<NBLK, 256, 0, stream>>>(y2s, t2sc, t2sh, W12, b12, y3s);
  s_stats_final<<<512, 256, 0, stream>>>(y3s, g12, be12, (float*)d_out);
}

// Round 16
// 432.365 us; speedup vs baseline: 1.4158x; 1.2245x over previous
//
#include <hip/hip_runtime.h>
#include <cstdint>
#include <cstddef>

#define NPTS 8192
#define BATCH 16
#define MS 128
#define KNB 64
#define NBLK (BATCH * MS)   // 2048

// ---------------- DPP wave reductions (VALU-speed, no LDS crossbar) ----------
__device__ __forceinline__ float dpp_wave_max_f32(float v) {
  v = fmaxf(v, __int_as_float(__builtin_amdgcn_update_dpp((int)0xff800000, __float_as_int(v), 0x111, 0xf, 0xf, false)));
  v = fmaxf(v, __int_as_float(__builtin_amdgcn_update_dpp((int)0xff800000, __float_as_int(v), 0x112, 0xf, 0xf, false)));
  v = fmaxf(v, __int_as_float(__builtin_amdgcn_update_dpp((int)0xff800000, __float_as_int(v), 0x114, 0xf, 0xf, false)));
  v = fmaxf(v, __int_as_float(__builtin_amdgcn_update_dpp((int)0xff800000, __float_as_int(v), 0x118, 0xf, 0xf, false)));
  v = fmaxf(v, __int_as_float(__builtin_amdgcn_update_dpp((int)0xff800000, __float_as_int(v), 0x142, 0xa, 0xf, false)));
  v = fmaxf(v, __int_as_float(__builtin_amdgcn_update_dpp((int)0xff800000, __float_as_int(v), 0x143, 0xc, 0xf, false)));
  return v;  // lane 63
}

__device__ __forceinline__ float dpp_wave_min_f32(float v) {
  v = fminf(v, __int_as_float(__builtin_amdgcn_update_dpp(0x7f800000, __float_as_int(v), 0x111, 0xf, 0xf, false)));
  v = fminf(v, __int_as_float(__builtin_amdgcn_update_dpp(0x7f800000, __float_as_int(v), 0x112, 0xf, 0xf, false)));
  v = fminf(v, __int_as_float(__builtin_amdgcn_update_dpp(0x7f800000, __float_as_int(v), 0x114, 0xf, 0xf, false)));
  v = fminf(v, __int_as_float(__builtin_amdgcn_update_dpp(0x7f800000, __float_as_int(v), 0x118, 0xf, 0xf, false)));
  v = fminf(v, __int_as_float(__builtin_amdgcn_update_dpp(0x7f800000, __float_as_int(v), 0x142, 0xa, 0xf, false)));
  v = fminf(v, __int_as_float(__builtin_amdgcn_update_dpp(0x7f800000, __float_as_int(v), 0x143, 0xc, 0xf, false)));
  return v;  // lane 63
}

__device__ __forceinline__ unsigned dpp_wave_min_u32(unsigned v) {
  unsigned o;
  o = (unsigned)__builtin_amdgcn_update_dpp((int)0xffffffffu, (int)v, 0x111, 0xf, 0xf, false); v = (o < v) ? o : v;
  o = (unsigned)__builtin_amdgcn_update_dpp((int)0xffffffffu, (int)v, 0x112, 0xf, 0xf, false); v = (o < v) ? o : v;
  o = (unsigned)__builtin_amdgcn_update_dpp((int)0xffffffffu, (int)v, 0x114, 0xf, 0xf, false); v = (o < v) ? o : v;
  o = (unsigned)__builtin_amdgcn_update_dpp((int)0xffffffffu, (int)v, 0x118, 0xf, 0xf, false); v = (o < v) ? o : v;
  o = (unsigned)__builtin_amdgcn_update_dpp((int)0xffffffffu, (int)v, 0x142, 0xa, 0xf, false); v = (o < v) ? o : v;
  o = (unsigned)__builtin_amdgcn_update_dpp((int)0xffffffffu, (int)v, 0x143, 0xc, 0xf, false); v = (o < v) ? o : v;
  return v;  // lane 63
}

__device__ __forceinline__ float dpp_row_max_f32(float v) {  // lane 15 of each row
  v = fmaxf(v, __int_as_float(__builtin_amdgcn_update_dpp((int)0xff800000, __float_as_int(v), 0x111, 0xf, 0xf, false)));
  v = fmaxf(v, __int_as_float(__builtin_amdgcn_update_dpp((int)0xff800000, __float_as_int(v), 0x112, 0xf, 0xf, false)));
  v = fmaxf(v, __int_as_float(__builtin_amdgcn_update_dpp((int)0xff800000, __float_as_int(v), 0x114, 0xf, 0xf, false)));
  v = fmaxf(v, __int_as_float(__builtin_amdgcn_update_dpp((int)0xff800000, __float_as_int(v), 0x118, 0xf, 0xf, false)));
  return v;
}

__device__ __forceinline__ unsigned dpp_row_min_u32(unsigned v) {  // lane 15 of each row
  unsigned o;
  o = (unsigned)__builtin_amdgcn_update_dpp((int)0xffffffffu, (int)v, 0x111, 0xf, 0xf, false); v = (o < v) ? o : v;
  o = (unsigned)__builtin_amdgcn_update_dpp((int)0xffffffffu, (int)v, 0x112, 0xf, 0xf, false); v = (o < v) ? o : v;
  o = (unsigned)__builtin_amdgcn_update_dpp((int)0xffffffffu, (int)v, 0x114, 0xf, 0xf, false); v = (o < v) ? o : v;
  o = (unsigned)__builtin_amdgcn_update_dpp((int)0xffffffffu, (int)v, 0x118, 0xf, 0xf, false); v = (o < v) ? o : v;
  return v;
}

// ---------------------------------------------------------------- FPS
// Round-12 verified version (single dispatch; empirical floor ~160us).
#define FPS_STEP(J)                                                        \
  {                                                                        \
    const float4 p = pts4[J * 1024 + t];                                   \
    const float dx = p.x - lx;                                             \
    const float dy = p.y - ly;                                             \
    const float dz = p.z - lz;                                             \
    const float d = dx * dx + dy * dy + dz * dz;                           \
    md##J = fminf(md##J, d);                                               \
  }

#define FPS_RESCAN(J)                                                      \
  if (md##J == wv) best = (unsigned)(J * 1024 + t);

__global__ __launch_bounds__(1024, 4) void fps_kernel(const float* __restrict__ pos,
                                                      float* __restrict__ sp) {
#pragma clang fp contract(off)
  extern __shared__ float4 pts4[];  // 8192 * 16B = 128KB dynamic
  __shared__ float wval[2][16];
  __shared__ unsigned widx[2][16];
  const int b = blockIdx.x;
  const float* P = pos + (size_t)b * NPTS * 3;
  const int t = threadIdx.x;
  const int wave = t >> 6;
  const int lane = t & 63;
  float md0 = 1e10f, md1 = 1e10f, md2 = 1e10f, md3 = 1e10f;
  float md4 = 1e10f, md5 = 1e10f, md6 = 1e10f, md7 = 1e10f;
  for (int i = t; i < NPTS; i += 1024)
    pts4[i] = make_float4(P[i * 3 + 0], P[i * 3 + 1], P[i * 3 + 2], 0.f);
  float lx = P[0], ly = P[1], lz = P[2];
  __syncthreads();
  for (int it = 0; it < MS; ++it) {
    if (t == 0) {
      sp[((size_t)b * MS + it) * 3 + 0] = lx;
      sp[((size_t)b * MS + it) * 3 + 1] = ly;
      sp[((size_t)b * MS + it) * 3 + 2] = lz;
    }
    FPS_STEP(0) FPS_STEP(1) FPS_STEP(2) FPS_STEP(3)
    FPS_STEP(4) FPS_STEP(5) FPS_STEP(6) FPS_STEP(7)
    const float m01 = fmaxf(md0, md1), m23 = fmaxf(md2, md3);
    const float m45 = fmaxf(md4, md5), m67 = fmaxf(md6, md7);
    const float bv = fmaxf(fmaxf(m01, m23), fmaxf(m45, m67));
    const float wv = __int_as_float(
        __builtin_amdgcn_readlane(__float_as_int(dpp_wave_max_f32(bv)), 63));
    unsigned best = 0xffffffffu;
    if (bv == wv) {
      FPS_RESCAN(7) FPS_RESCAN(6) FPS_RESCAN(5) FPS_RESCAN(4)
      FPS_RESCAN(3) FPS_RESCAN(2) FPS_RESCAN(1) FPS_RESCAN(0)
    }
    const unsigned wi =
        (unsigned)__builtin_amdgcn_readlane((int)dpp_wave_min_u32(best), 63);
    const int par = it & 1;
    if (lane == 0) { wval[par][wave] = wv; widx[par][wave] = wi; }
    __syncthreads();
    const float a = wval[par][lane & 15];
    const float M = __int_as_float(
        __builtin_amdgcn_readlane(__float_as_int(dpp_row_max_f32(a)), 15));
    const unsigned c2 = (a == M) ? widx[par][lane & 15] : 0xffffffffu;
    const unsigned idx =
        (unsigned)__builtin_amdgcn_readlane((int)dpp_row_min_u32(c2), 15);
    const float4 c = pts4[idx];
    lx = c.x; ly = c.y; lz = c.z;
  }
}

// ---------------------------------------------------------------- kNN top-64 v3
// Barrier-free per-wave tournament + exact parallel merge (round-12, verified).
__global__ __launch_bounds__(256) void knn_kernel(const float* __restrict__ pos,
                                                  const float* __restrict__ xf,
                                                  const float* __restrict__ sp,
                                                  float* __restrict__ gf0,
                                                  float* __restrict__ sqsel) {
#pragma clang fp contract(off)
  __shared__ float sqv[NPTS + 32];            // swizzled: addr(i) = i + (i>>8)
  __shared__ unsigned long long wlist[4][KNB];
  __shared__ unsigned long long selk[KNB];
  const int bm = blockIdx.x;
  const int b = bm >> 7;
  const float* P = pos + (size_t)b * NPTS * 3;
  const float sx = sp[bm * 3 + 0], sy = sp[bm * 3 + 1], sz = sp[bm * 3 + 2];
  const float nsp = sx * sx + sy * sy + sz * sz;
  const int t = threadIdx.x;
  const int wave = t >> 6;
  const int lane = t & 63;
  float cv;
  unsigned ci;
  {
    unsigned long long k0 = ~0ULL;
    for (int j = 0; j < 32; ++j) {
      const int i = j * 256 + t;
      const float qx = P[i * 3 + 0], qy = P[i * 3 + 1], qz = P[i * 3 + 2];
      const float npos = qx * qx + qy * qy + qz * qz;
      const float dt = sx * qx + sy * qy + sz * qz;
      float sq = (nsp + npos) - 2.0f * dt;  // matches ||a||^2+||b||^2-2ab order
      sq = fmaxf(sq, 0.0f);
      sqv[i + j] = sq;                      // swizzle: i>>8 == j
      const unsigned long long key =
          ((unsigned long long)__float_as_uint(sq) << 32) | (unsigned)i;
      if (key < k0) k0 = key;
    }
    cv = __uint_as_float((unsigned)(k0 >> 32));
    ci = (unsigned)k0;
  }
  __syncthreads();
  unsigned cmask = 0u;
  for (int round = 0; round < KNB; ++round) {
    const float wv = __int_as_float(
        __builtin_amdgcn_readlane(__float_as_int(dpp_wave_min_f32(cv)), 63));
    const unsigned sel = (cv == wv) ? ci : 0xffffffffu;
    const unsigned wi =
        (unsigned)__builtin_amdgcn_readlane((int)dpp_wave_min_u32(sel), 63);
    if (lane == 0)
      wlist[wave][round] =
          ((unsigned long long)__float_as_uint(wv) << 32) | wi;
    const int col = (int)(wi & 255u);
    const int ownerLane = col & 63;
    const unsigned jsel = wi >> 8;
    if (lane == ownerLane) cmask |= (1u << jsel);
    const unsigned omask =
        (unsigned)__builtin_amdgcn_readlane((int)cmask, ownerLane);
    float v = __uint_as_float(0x7f800000u);
    unsigned ii = 0xffffffffu;
    if (lane < 32 && !((omask >> lane) & 1u)) {
      const int i = lane * 256 + col;
      v = sqv[i + lane];
      ii = (unsigned)i;
    }
    const float mv = __int_as_float(
        __builtin_amdgcn_readlane(__float_as_int(dpp_wave_min_f32(v)), 63));
    const unsigned s2 = (v == mv) ? ii : 0xffffffffu;
    const unsigned mi =
        (unsigned)__builtin_amdgcn_readlane((int)dpp_wave_min_u32(s2), 63);
    if (lane == ownerLane) { cv = mv; ci = mi; }
  }
  __syncthreads();
  {
    const int w = wave, r = lane;
    const unsigned long long e = wlist[w][r];
    int rank = r;
#pragma unroll
    for (int w2 = 0; w2 < 4; ++w2) {
      if (w2 == w) continue;
      int lo = 0;
#pragma unroll
      for (int step = 32; step > 0; step >>= 1)
        if (lo + step <= KNB && wlist[w2][lo + step - 1] < e) lo += step;
      rank += lo;
    }
    if (rank < KNB) selk[rank] = e;
  }
  __syncthreads();
  if (t < KNB) {
    const unsigned long long e = selk[t];
    const int i = (int)(e & 0xffffffffu);
    const float* X = xf + (size_t)b * NPTS * 3;
    const size_t base = ((size_t)bm * KNB + t) * 6;
    gf0[base + 0] = P[i * 3 + 0] - sx;
    gf0[base + 1] = P[i * 3 + 1] - sy;
    gf0[base + 2] = P[i * 3 + 2] - sz;
    gf0[base + 3] = X[i * 3 + 0];
    gf0[base + 4] = X[i * 3 + 1];
    gf0[base + 5] = X[i * 3 + 2];
    sqsel[(size_t)bm * KNB + t] = __uint_as_float((unsigned)(e >> 32));
  }
}

// ================================================================ chain
__global__ __launch_bounds__(256) void l1_kernel(
    const float* __restrict__ gf0, const float* __restrict__ W0,
    const float* __restrict__ B0,
    float* __restrict__ psum, float* __restrict__ psq,
    float* __restrict__ y1pre) {
  __shared__ float in6[64 * 8];
  __shared__ float wbuf[384];
  __shared__ float out[64 * 65];
  const int blk = blockIdx.x;
  const int t = threadIdx.x;
  const float* G = gf0 + (size_t)blk * 384;
  for (int i = t; i < 384; i += 256) in6[(i / 6) * 8 + (i % 6)] = G[i];
  for (int i = t; i < 384; i += 256) wbuf[i] = W0[i];
  __syncthreads();
  const int r = t >> 2;
  const int c0 = (t & 3) * 16;
  float acc[16];
#pragma unroll
  for (int j = 0; j < 16; ++j) acc[j] = B0[c0 + j];
  for (int cin = 0; cin < 6; ++cin) {
    const float a = in6[r * 8 + cin];
#pragma unroll
    for (int j = 0; j < 16; ++j) acc[j] = fmaf(a, wbuf[cin * 64 + c0 + j], acc[j]);
  }
#pragma unroll
  for (int j = 0; j < 16; ++j) out[r * 65 + c0 + j] = acc[j];
  __syncthreads();
  if (t < 64) {
    float s = 0.f, q = 0.f;
    for (int r2 = 0; r2 < 64; ++r2) { const float v = out[r2 * 65 + t]; s += v; q += v * v; }
    psum[(size_t)t * NBLK + blk] = s;
    psq[(size_t)t * NBLK + blk] = q;
  }
  float* Y = y1pre + (size_t)blk * 4096;
  for (int i = t; i < 4096; i += 256) Y[i] = out[(i >> 6) * 65 + (i & 63)];
}

__global__ __launch_bounds__(256) void l2_kernel(
    const float* __restrict__ ypre, const float* __restrict__ sc,
    const float* __restrict__ sh, const float* __restrict__ W1,
    const float* __restrict__ B1,
    float* __restrict__ psum, float* __restrict__ psq,
    float* __restrict__ yout) {
  __shared__ float As[64 * 68];
  __shared__ float Bs[64 * 64];
  __shared__ float out[64 * 68];
  const int blk = blockIdx.x;
  const int t = threadIdx.x;
  const float* Y = ypre + (size_t)blk * 4096;
  for (int i = t; i < 4096; i += 256) {
    const int c = i & 63;
    As[(i >> 6) * 68 + c] = fmaxf(fmaf(Y[i], sc[c], sh[c]), 0.f);
  }
  for (int i = t; i < 4096; i += 256) Bs[i] = W1[i];
  __syncthreads();
  const int tr = t >> 4;
  const int tc4 = (t & 15) * 4;
  float acc[4][4];
#pragma unroll
  for (int s = 0; s < 4; ++s)
#pragma unroll
    for (int j = 0; j < 4; ++j) acc[s][j] = B1[tc4 + j];
  for (int k0 = 0; k0 < 64; k0 += 4) {
    float4 av[4];
#pragma unroll
    for (int s = 0; s < 4; ++s)
      av[s] = *reinterpret_cast<const float4*>(&As[(tr + 16 * s) * 68 + k0]);
#pragma unroll
    for (int kk = 0; kk < 4; ++kk) {
      const float4 bv = *reinterpret_cast<const float4*>(&Bs[(k0 + kk) * 64 + tc4]);
#pragma unroll
      for (int s = 0; s < 4; ++s) {
        const float a = (kk == 0) ? av[s].x : (kk == 1) ? av[s].y
                       : (kk == 2) ? av[s].z : av[s].w;
        acc[s][0] = fmaf(a, bv.x, acc[s][0]);
        acc[s][1] = fmaf(a, bv.y, acc[s][1]);
        acc[s][2] = fmaf(a, bv.z, acc[s][2]);
        acc[s][3] = fmaf(a, bv.w, acc[s][3]);
      }
    }
  }
#pragma unroll
  for (int s = 0; s < 4; ++s) {
    float4 o;
    o.x = acc[s][0]; o.y = acc[s][1]; o.z = acc[s][2]; o.w = acc[s][3];
    *reinterpret_cast<float4*>(&out[(tr + 16 * s) * 68 + tc4]) = o;
  }
  __syncthreads();
  if (t < 64) {
    float s = 0.f, q = 0.f;
    for (int r2 = 0; r2 < 64; ++r2) { const float v = out[r2 * 68 + t]; s += v; q += v * v; }
    psum[(size_t)t * NBLK + blk] = s;
    psq[(size_t)t * NBLK + blk] = q;
  }
  float* O = yout + (size_t)blk * 4096;
  for (int i = t; i < 4096; i += 256) O[i] = out[(i >> 6) * 68 + (i & 63)];
}

__global__ __launch_bounds__(256) void l3_kernel(
    const float* __restrict__ ypre, const float* __restrict__ sc,
    const float* __restrict__ sh, const float* __restrict__ W2,
    const float* __restrict__ B2,
    float* __restrict__ psum, float* __restrict__ psq,
    float* __restrict__ yout) {
  __shared__ float As[64 * 68];
  __shared__ float Bs[64 * 64];
  __shared__ float out[64 * 68];
  const int blk = blockIdx.x;
  const int t = threadIdx.x;
  const float* Y = ypre + (size_t)blk * 4096;
  for (int i = t; i < 4096; i += 256) {
    const int c = i & 63;
    As[(i >> 6) * 68 + c] = fmaxf(fmaf(Y[i], sc[c], sh[c]), 0.f);
  }
  const int tr = t >> 4;
  const int tc4 = (t & 15) * 4;
  for (int hc = 0; hc < 2; ++hc) {
    __syncthreads();
    for (int i = t; i < 4096; i += 256)
      Bs[i] = W2[(i >> 6) * 128 + hc * 64 + (i & 63)];
    __syncthreads();
    float acc[4][4];
#pragma unroll
    for (int s = 0; s < 4; ++s)
#pragma unroll
      for (int j = 0; j < 4; ++j) acc[s][j] = B2[hc * 64 + tc4 + j];
    for (int k0 = 0; k0 < 64; k0 += 4) {
      float4 av[4];
#pragma unroll
      for (int s = 0; s < 4; ++s)
        av[s] = *reinterpret_cast<const float4*>(&As[(tr + 16 * s) * 68 + k0]);
#pragma unroll
      for (int kk = 0; kk < 4; ++kk) {
        const float4 bv = *reinterpret_cast<const float4*>(&Bs[(k0 + kk) * 64 + tc4]);
#pragma unroll
        for (int s = 0; s < 4; ++s) {
          const float a = (kk == 0) ? av[s].x : (kk == 1) ? av[s].y
                         : (kk == 2) ? av[s].z : av[s].w;
          acc[s][0] = fmaf(a, bv.x, acc[s][0]);
          acc[s][1] = fmaf(a, bv.y, acc[s][1]);
          acc[s][2] = fmaf(a, bv.z, acc[s][2]);
          acc[s][3] = fmaf(a, bv.w, acc[s][3]);
        }
      }
    }
#pragma unroll
    for (int s = 0; s < 4; ++s) {
      float4 o;
      o.x = acc[s][0]; o.y = acc[s][1]; o.z = acc[s][2]; o.w = acc[s][3];
      *reinterpret_cast<float4*>(&out[(tr + 16 * s) * 68 + tc4]) = o;
    }
    __syncthreads();
    if (t < 64) {
      float s = 0.f, q = 0.f;
      for (int r2 = 0; r2 < 64; ++r2) { const float v = out[r2 * 68 + t]; s += v; q += v * v; }
      psum[(size_t)(hc * 64 + t) * NBLK + blk] = s;
      psq[(size_t)(hc * 64 + t) * NBLK + blk] = q;
    }
    float* O = yout + (size_t)blk * 8192;
    for (int i = t; i < 4096; i += 256)
      O[(i >> 6) * 128 + hc * 64 + (i & 63)] = out[(i >> 6) * 68 + (i & 63)];
  }
}

__global__ __launch_bounds__(128) void l4s1_kernel(
    const float* __restrict__ y3pre, const float* __restrict__ sc3,
    const float* __restrict__ sh3, const float* __restrict__ sqsel,
    const float* __restrict__ sp, const float* __restrict__ W,
    const float* __restrict__ bia, float* __restrict__ y1) {
  __shared__ float sqs[64];
  __shared__ float row[132];
  const int blk = blockIdx.x;
  const int t = threadIdx.x;
  if (t < 64) sqs[t] = sqsel[(size_t)blk * 64 + t];
  __syncthreads();
  const float scv = sc3[t], shv = sh3[t];
  const float* Y = y3pre + (size_t)blk * 8192;
  float mx = -1e8f;
  for (int r = 0; r < 64; ++r) {
    const float act = fmaxf(fmaf(Y[r * 128 + t], scv, shv), 0.f);
    const float v = (sqs[r] <= 0.16f) ? act : -1e8f;
    mx = fmaxf(mx, v);
  }
  if (t < 3) row[t] = sp[(size_t)blk * 3 + t];
  row[3 + t] = mx;
  __syncthreads();
  float acc = bia[t];
  for (int cin = 0; cin < 131; ++cin) acc = fmaf(row[cin], W[(size_t)cin * 128 + t], acc);
  y1[(size_t)blk * 128 + t] = acc;
}

__global__ __launch_bounds__(256) void p_stats(const float* __restrict__ psum,
                                               const float* __restrict__ psq,
                                               float invN,
                                               const float* __restrict__ g,
                                               const float* __restrict__ be,
                                               float* __restrict__ sc,
                                               float* __restrict__ sh) {
  const int c = blockIdx.x;
  const int t = threadIdx.x;
  double s = 0.0, q = 0.0;
  for (int k = t; k < NBLK; k += 256) {
    s += (double)psum[(size_t)c * NBLK + k];
    q += (double)psq[(size_t)c * NBLK + k];
  }
  __shared__ double ss[256], qq[256];
  ss[t] = s;
  qq[t] = q;
  __syncthreads();
  for (int st = 128; st > 0; st >>= 1) {
    if (t < st) { ss[t] += ss[t + st]; qq[t] += qq[t + st]; }
    __syncthreads();
  }
  if (t == 0) {
    const double mean = ss[0] * (double)invN;
    double var = qq[0] * (double)invN - mean * mean;
    if (var < 0.0) var = 0.0;
    const float scl = (float)((double)g[c] / sqrt(var + 1e-5));
    sc[c] = scl;
    sh[c] = be[c] - (float)mean * scl;
  }
}

// ---------------------------------------------------------------- stage 1
__global__ __launch_bounds__(128) void s2_kernel(const float* __restrict__ y1,
                                                 const float* __restrict__ sc, const float* __restrict__ sh,
                                                 const float* __restrict__ W, const float* __restrict__ bia,
                                                 float* __restrict__ y2) {
  __shared__ float row[128];
  const int rowid = blockIdx.x;
  const int t = threadIdx.x;
  row[t] = fmaxf(fmaf(y1[(size_t)rowid * 128 + t], sc[t], sh[t]), 0.f);
  __syncthreads();
  float acc = bia[t];
  for (int cin = 0; cin < 128; ++cin) acc = fmaf(row[cin], W[(size_t)cin * 128 + t], acc);
  y2[(size_t)rowid * 128 + t] = acc;
}

__global__ __launch_bounds__(256) void s3_kernel(const float* __restrict__ y2,
                                                 const float* __restrict__ sc, const float* __restrict__ sh,
                                                 const float* __restrict__ W, const float* __restrict__ bia,
                                                 float* __restrict__ y3) {
  __shared__ float row[128];
  const int rowid = blockIdx.x;
  const int t = threadIdx.x;
  if (t < 128) row[t] = fmaxf(fmaf(y2[(size_t)rowid * 128 + t], sc[t], sh[t]), 0.f);
  __syncthreads();
  for (int h = 0; h < 2; ++h) {
    const int c = h * 256 + t;
    float acc = bia[c];
    for (int cin = 0; cin < 128; ++cin) acc = fmaf(row[cin], W[(size_t)cin * 512 + c], acc);
    y3[(size_t)rowid * 512 + c] = acc;
  }
}

__global__ __launch_bounds__(256) void s_stats(const float* __restrict__ y, int C, int rows,
                                               const float* __restrict__ g, const float* __restrict__ be,
                                               float* __restrict__ sc, float* __restrict__ sh) {
  const int c = blockIdx.x;
  const int t = threadIdx.x;
  double s = 0.0, q = 0.0;
  for (int r2 = t; r2 < rows; r2 += 256) {
    const double v = (double)y[(size_t)r2 * C + c];
    s += v;
    q += v * v;
  }
  __shared__ double ss[256], qq[256];
  ss[t] = s;
  qq[t] = q;
  __syncthreads();
  for (int st = 128; st > 0; st >>= 1) {
    if (t < st) { ss[t] += ss[t + st]; qq[t] += qq[t + st]; }
    __syncthreads();
  }
  if (t == 0) {
    const double mean = ss[0] / rows;
    double var = qq[0] / rows - mean * mean;
    if (var < 0.0) var = 0.0;
    const float scl = (float)((double)g[c] / sqrt(var + 1e-5));
    sc[c] = scl;
    sh[c] = be[c] - (float)mean * scl;
  }
}

__global__ __launch_bounds__(256) void s_stats_final(const float* __restrict__ y3,
                                                     const float* __restrict__ g,
                                                     const float* __restrict__ be,
                                                     float* __restrict__ out) {
  const int c = blockIdx.x;
  const int t = threadIdx.x;
  double s = 0.0, q = 0.0;
  for (int r2 = t; r2 < NBLK; r2 += 256) {
    const double v = (double)y3[(size_t)r2 * 512 + c];
    s += v;
    q += v * v;
  }
  __shared__ double ss[256], qq[256];
  __shared__ float sscl, sshv;
  ss[t] = s;
  qq[t] = q;
  __syncthreads();
  for (int st = 128; st > 0; st >>= 1) {
    if (t < st) { ss[t] += ss[t + st]; qq[t] += qq[t + st]; }
    __syncthreads();
  }
  if (t == 0) {
    const double mean = ss[0] / NBLK;
    double var = qq[0] / NBLK - mean * mean;
    if (var < 0.0) var = 0.0;
    const float scl = (float)((double)g[c] / sqrt(var + 1e-5));
    sscl = scl;
    sshv = be[c] - (float)mean * scl;
  }
  __syncthreads();
  const float scl = sscl, shv = sshv;
  float mx = -3.402823466e+38f;
  for (int k = 0; k < 8; ++k) {
    const int r = t * 8 + k;
    const float v = fmaxf(fmaf(y3[(size_t)r * 512 + c], scl, shv), 0.f);
    mx = fmaxf(mx, v);
  }
  __shared__ float pmax[256];
  pmax[t] = mx;
  __syncthreads();
  if (t < 16) {
    float m = -3.402823466e+38f;
    for (int j = 0; j < 16; ++j) m = fmaxf(m, pmax[t * 16 + j]);
    out[(size_t)t * 512 + c] = m;
  }
  if (c == 0 && t < 48) out[8192 + t] = 0.f;  // pos_out zeros
}

extern "C" void kernel_launch(void* const* d_in, const int* in_sizes, int n_in,
                              void* d_out, int out_size, void* d_ws, size_t ws_size,
                              hipStream_t stream) {
  const float* x    = (const float*)d_in[0];
  const float* pos  = (const float*)d_in[1];
  const float* W00  = (const float*)d_in[2];
  const float* b00  = (const float*)d_in[3];
  const float* g00  = (const float*)d_in[4];
  const float* be00 = (const float*)d_in[5];
  const float* W01  = (const float*)d_in[6];
  const float* b01  = (const float*)d_in[7];
  const float* g01  = (const float*)d_in[8];
  const float* be01 = (const float*)d_in[9];
  const float* W02  = (const float*)d_in[10];
  const float* b02  = (const float*)d_in[11];
  const float* g02  = (const float*)d_in[12];
  const float* be02 = (const float*)d_in[13];
  const float* W10  = (const float*)d_in[14];
  const float* b10  = (const float*)d_in[15];
  const float* g10  = (const float*)d_in[16];
  const float* be10 = (const float*)d_in[17];
  const float* W11  = (const float*)d_in[18];
  const float* b11  = (const float*)d_in[19];
  const float* g11  = (const float*)d_in[20];
  const float* be11 = (const float*)d_in[21];
  const float* W12  = (const float*)d_in[22];
  const float* b12  = (const float*)d_in[23];
  const float* g12  = (const float*)d_in[24];
  const float* be12 = (const float*)d_in[25];

  float* w = (float*)d_ws;
  float* sp    = w;                  // 6144
  float* gf0   = sp + 6144;          // 786432
  float* sqsel = gf0 + 786432;       // 131072
  float* x1    = sqsel + 131072;     // 262144 (unused)
  float* parts = x1 + 262144;        // 524288
  float* psum  = parts;
  float* psq   = parts + 128 * NBLK;
  float* st    = parts + 524288;     // 2048
  float* sc1 = st + 0,    *sh1 = st + 64;
  float* sc2 = st + 128,  *sh2 = st + 192;
  float* sc3 = st + 256,  *sh3 = st + 384;
  float* t1sc = st + 512, *t1sh = st + 640;
  float* t2sc = st + 768, *t2sh = st + 896;
  float* y1s = st + 2048;            // 262144
  float* y2s = y1s + 262144;         // 262144
  float* y3s = y2s + 262144;         // 1048576
  const size_t BASE = 3284992;
  float* y1pre = w + BASE;                       // 8388608
  float* y2pre = y1pre + 8388608;                // 8388608
  float* y3pre = y2pre + 8388608;                // 16777216

  fps_kernel<<<BATCH, 1024, NPTS * sizeof(float4), stream>>>(pos, sp);
  knn_kernel<<<BATCH * MS, 256, 0, stream>>>(pos, x, sp, gf0, sqsel);

  const float invN0 = 1.0f / (float)(NBLK * KNB);  // 1/131072
  l1_kernel<<<NBLK, 256, 0, stream>>>(gf0, W00, b00, psum, psq, y1pre);
  p_stats<<<64, 256, 0, stream>>>(psum, psq, invN0, g00, be00, sc1, sh1);
  l2_kernel<<<NBLK, 256, 0, stream>>>(y1pre, sc1, sh1, W01, b01, psum, psq, y2pre);
  p_stats<<<64, 256, 0, stream>>>(psum, psq, invN0, g01, be01, sc2, sh2);
  l3_kernel<<<NBLK, 256, 0, stream>>>(y2pre, sc2, sh2, W02, b02, psum, psq, y3pre);
  p_stats<<<128, 256, 0, stream>>>(psum, psq, invN0, g02, be02, sc3, sh3);
  l4s1_kernel<<<NBLK, 128, 0, stream>>>(y3pre, sc3, sh3, sqsel, sp, W10, b10, y1s);

  s_stats<<<128, 256, 0, stream>>>(y1s, 128, NBLK, g10, be10, t1sc, t1sh);
  s2_kernel<<<NBLK, 128, 0, stream>>>(y1s, t1sc, t1sh, W11, b11, y2s);
  s_stats<<<128, 256, 0, stream>>>(y2s, 128, NBLK, g11, be11, t2sc, t2sh);
  s3_kernel<<<NBLK, 256, 0, stream>>>(y2s, t2sc, t2sh, W12, b12, y3s);
  s_stats_final<<<512, 256, 0, stream>>>(y3s, g12, be12, (float*)d_out);
}

// Round 17
// 415.762 us; speedup vs baseline: 1.4723x; 1.0399x over previous
//
#include <hip/hip_runtime.h>
#include <cstdint>
#include <cstddef>

#define NPTS 8192
#define BATCH 16
#define MS 128
#define KNB 64
#define NBLK (BATCH * MS)   // 2048

// ---------------- DPP wave reductions (VALU-speed, no LDS crossbar) ----------
__device__ __forceinline__ float dpp_wave_max_f32(float v) {
  v = fmaxf(v, __int_as_float(__builtin_amdgcn_update_dpp((int)0xff800000, __float_as_int(v), 0x111, 0xf, 0xf, false)));
  v = fmaxf(v, __int_as_float(__builtin_amdgcn_update_dpp((int)0xff800000, __float_as_int(v), 0x112, 0xf, 0xf, false)));
  v = fmaxf(v, __int_as_float(__builtin_amdgcn_update_dpp((int)0xff800000, __float_as_int(v), 0x114, 0xf, 0xf, false)));
  v = fmaxf(v, __int_as_float(__builtin_amdgcn_update_dpp((int)0xff800000, __float_as_int(v), 0x118, 0xf, 0xf, false)));
  v = fmaxf(v, __int_as_float(__builtin_amdgcn_update_dpp((int)0xff800000, __float_as_int(v), 0x142, 0xa, 0xf, false)));
  v = fmaxf(v, __int_as_float(__builtin_amdgcn_update_dpp((int)0xff800000, __float_as_int(v), 0x143, 0xc, 0xf, false)));
  return v;  // lane 63
}

__device__ __forceinline__ float dpp_wave_min_f32(float v) {
  v = fminf(v, __int_as_float(__builtin_amdgcn_update_dpp(0x7f800000, __float_as_int(v), 0x111, 0xf, 0xf, false)));
  v = fminf(v, __int_as_float(__builtin_amdgcn_update_dpp(0x7f800000, __float_as_int(v), 0x112, 0xf, 0xf, false)));
  v = fminf(v, __int_as_float(__builtin_amdgcn_update_dpp(0x7f800000, __float_as_int(v), 0x114, 0xf, 0xf, false)));
  v = fminf(v, __int_as_float(__builtin_amdgcn_update_dpp(0x7f800000, __float_as_int(v), 0x118, 0xf, 0xf, false)));
  v = fminf(v, __int_as_float(__builtin_amdgcn_update_dpp(0x7f800000, __float_as_int(v), 0x142, 0xa, 0xf, false)));
  v = fminf(v, __int_as_float(__builtin_amdgcn_update_dpp(0x7f800000, __float_as_int(v), 0x143, 0xc, 0xf, false)));
  return v;  // lane 63
}

__device__ __forceinline__ unsigned dpp_wave_min_u32(unsigned v) {
  unsigned o;
  o = (unsigned)__builtin_amdgcn_update_dpp((int)0xffffffffu, (int)v, 0x111, 0xf, 0xf, false); v = (o < v) ? o : v;
  o = (unsigned)__builtin_amdgcn_update_dpp((int)0xffffffffu, (int)v, 0x112, 0xf, 0xf, false); v = (o < v) ? o : v;
  o = (unsigned)__builtin_amdgcn_update_dpp((int)0xffffffffu, (int)v, 0x114, 0xf, 0xf, false); v = (o < v) ? o : v;
  o = (unsigned)__builtin_amdgcn_update_dpp((int)0xffffffffu, (int)v, 0x118, 0xf, 0xf, false); v = (o < v) ? o : v;
  o = (unsigned)__builtin_amdgcn_update_dpp((int)0xffffffffu, (int)v, 0x142, 0xa, 0xf, false); v = (o < v) ? o : v;
  o = (unsigned)__builtin_amdgcn_update_dpp((int)0xffffffffu, (int)v, 0x143, 0xc, 0xf, false); v = (o < v) ? o : v;
  return v;  // lane 63
}

__device__ __forceinline__ float dpp_row_max_f32(float v) {  // lane 15 of each row
  v = fmaxf(v, __int_as_float(__builtin_amdgcn_update_dpp((int)0xff800000, __float_as_int(v), 0x111, 0xf, 0xf, false)));
  v = fmaxf(v, __int_as_float(__builtin_amdgcn_update_dpp((int)0xff800000, __float_as_int(v), 0x112, 0xf, 0xf, false)));
  v = fmaxf(v, __int_as_float(__builtin_amdgcn_update_dpp((int)0xff800000, __float_as_int(v), 0x114, 0xf, 0xf, false)));
  v = fmaxf(v, __int_as_float(__builtin_amdgcn_update_dpp((int)0xff800000, __float_as_int(v), 0x118, 0xf, 0xf, false)));
  return v;
}

__device__ __forceinline__ unsigned dpp_row_min_u32(unsigned v) {  // lane 15 of each row
  unsigned o;
  o = (unsigned)__builtin_amdgcn_update_dpp((int)0xffffffffu, (int)v, 0x111, 0xf, 0xf, false); v = (o < v) ? o : v;
  o = (unsigned)__builtin_amdgcn_update_dpp((int)0xffffffffu, (int)v, 0x112, 0xf, 0xf, false); v = (o < v) ? o : v;
  o = (unsigned)__builtin_amdgcn_update_dpp((int)0xffffffffu, (int)v, 0x114, 0xf, 0xf, false); v = (o < v) ? o : v;
  o = (unsigned)__builtin_amdgcn_update_dpp((int)0xffffffffu, (int)v, 0x118, 0xf, 0xf, false); v = (o < v) ? o : v;
  return v;
}

// ---------------------------------------------------------------- FPS
// Round-12 verified version (single dispatch; empirical floor ~160us).
#define FPS_STEP(J)                                                        \
  {                                                                        \
    const float4 p = pts4[J * 1024 + t];                                   \
    const float dx = p.x - lx;                                             \
    const float dy = p.y - ly;                                             \
    const float dz = p.z - lz;                                             \
    const float d = dx * dx + dy * dy + dz * dz;                           \
    md##J = fminf(md##J, d);                                               \
  }

#define FPS_RESCAN(J)                                                      \
  if (md##J == wv) best = (unsigned)(J * 1024 + t);

__global__ __launch_bounds__(1024, 4) void fps_kernel(const float* __restrict__ pos,
                                                      float* __restrict__ sp) {
#pragma clang fp contract(off)
  extern __shared__ float4 pts4[];  // 8192 * 16B = 128KB dynamic
  __shared__ float wval[2][16];
  __shared__ unsigned widx[2][16];
  const int b = blockIdx.x;
  const float* P = pos + (size_t)b * NPTS * 3;
  const int t = threadIdx.x;
  const int wave = t >> 6;
  const int lane = t & 63;
  float md0 = 1e10f, md1 = 1e10f, md2 = 1e10f, md3 = 1e10f;
  float md4 = 1e10f, md5 = 1e10f, md6 = 1e10f, md7 = 1e10f;
  for (int i = t; i < NPTS; i += 1024)
    pts4[i] = make_float4(P[i * 3 + 0], P[i * 3 + 1], P[i * 3 + 2], 0.f);
  float lx = P[0], ly = P[1], lz = P[2];
  __syncthreads();
  for (int it = 0; it < MS; ++it) {
    if (t == 0) {
      sp[((size_t)b * MS + it) * 3 + 0] = lx;
      sp[((size_t)b * MS + it) * 3 + 1] = ly;
      sp[((size_t)b * MS + it) * 3 + 2] = lz;
    }
    FPS_STEP(0) FPS_STEP(1) FPS_STEP(2) FPS_STEP(3)
    FPS_STEP(4) FPS_STEP(5) FPS_STEP(6) FPS_STEP(7)
    const float m01 = fmaxf(md0, md1), m23 = fmaxf(md2, md3);
    const float m45 = fmaxf(md4, md5), m67 = fmaxf(md6, md7);
    const float bv = fmaxf(fmaxf(m01, m23), fmaxf(m45, m67));
    const float wv = __int_as_float(
        __builtin_amdgcn_readlane(__float_as_int(dpp_wave_max_f32(bv)), 63));
    unsigned best = 0xffffffffu;
    if (bv == wv) {
      FPS_RESCAN(7) FPS_RESCAN(6) FPS_RESCAN(5) FPS_RESCAN(4)
      FPS_RESCAN(3) FPS_RESCAN(2) FPS_RESCAN(1) FPS_RESCAN(0)
    }
    const unsigned wi =
        (unsigned)__builtin_amdgcn_readlane((int)dpp_wave_min_u32(best), 63);
    const int par = it & 1;
    if (lane == 0) { wval[par][wave] = wv; widx[par][wave] = wi; }
    __syncthreads();
    const float a = wval[par][lane & 15];
    const float M = __int_as_float(
        __builtin_amdgcn_readlane(__float_as_int(dpp_row_max_f32(a)), 15));
    const unsigned c2 = (a == M) ? widx[par][lane & 15] : 0xffffffffu;
    const unsigned idx =
        (unsigned)__builtin_amdgcn_readlane((int)dpp_row_min_u32(c2), 15);
    const float4 c = pts4[idx];
    lx = c.x; ly = c.y; lz = c.z;
  }
}

// ---------------------------------------------------------------- kNN top-64 v3
// Barrier-free per-wave tournament + exact parallel merge (round-12, verified).
__global__ __launch_bounds__(256) void knn_kernel(const float* __restrict__ pos,
                                                  const float* __restrict__ xf,
                                                  const float* __restrict__ sp,
                                                  float* __restrict__ gf0,
                                                  float* __restrict__ sqsel) {
#pragma clang fp contract(off)
  __shared__ float sqv[NPTS + 32];            // swizzled: addr(i) = i + (i>>8)
  __shared__ unsigned long long wlist[4][KNB];
  __shared__ unsigned long long selk[KNB];
  const int bm = blockIdx.x;
  const int b = bm >> 7;
  const float* P = pos + (size_t)b * NPTS * 3;
  const float sx = sp[bm * 3 + 0], sy = sp[bm * 3 + 1], sz = sp[bm * 3 + 2];
  const float nsp = sx * sx + sy * sy + sz * sz;
  const int t = threadIdx.x;
  const int wave = t >> 6;
  const int lane = t & 63;
  float cv;
  unsigned ci;
  {
    unsigned long long k0 = ~0ULL;
    for (int j = 0; j < 32; ++j) {
      const int i = j * 256 + t;
      const float qx = P[i * 3 + 0], qy = P[i * 3 + 1], qz = P[i * 3 + 2];
      const float npos = qx * qx + qy * qy + qz * qz;
      const float dt = sx * qx + sy * qy + sz * qz;
      float sq = (nsp + npos) - 2.0f * dt;  // matches ||a||^2+||b||^2-2ab order
      sq = fmaxf(sq, 0.0f);
      sqv[i + j] = sq;                      // swizzle: i>>8 == j
      const unsigned long long key =
          ((unsigned long long)__float_as_uint(sq) << 32) | (unsigned)i;
      if (key < k0) k0 = key;
    }
    cv = __uint_as_float((unsigned)(k0 >> 32));
    ci = (unsigned)k0;
  }
  __syncthreads();
  unsigned cmask = 0u;
  for (int round = 0; round < KNB; ++round) {
    const float wv = __int_as_float(
        __builtin_amdgcn_readlane(__float_as_int(dpp_wave_min_f32(cv)), 63));
    const unsigned sel = (cv == wv) ? ci : 0xffffffffu;
    const unsigned wi =
        (unsigned)__builtin_amdgcn_readlane((int)dpp_wave_min_u32(sel), 63);
    if (lane == 0)
      wlist[wave][round] =
          ((unsigned long long)__float_as_uint(wv) << 32) | wi;
    const int col = (int)(wi & 255u);
    const int ownerLane = col & 63;
    const unsigned jsel = wi >> 8;
    if (lane == ownerLane) cmask |= (1u << jsel);
    const unsigned omask =
        (unsigned)__builtin_amdgcn_readlane((int)cmask, ownerLane);
    float v = __uint_as_float(0x7f800000u);
    unsigned ii = 0xffffffffu;
    if (lane < 32 && !((omask >> lane) & 1u)) {
      const int i = lane * 256 + col;
      v = sqv[i + lane];
      ii = (unsigned)i;
    }
    const float mv = __int_as_float(
        __builtin_amdgcn_readlane(__float_as_int(dpp_wave_min_f32(v)), 63));
    const unsigned s2 = (v == mv) ? ii : 0xffffffffu;
    const unsigned mi =
        (unsigned)__builtin_amdgcn_readlane((int)dpp_wave_min_u32(s2), 63);
    if (lane == ownerLane) { cv = mv; ci = mi; }
  }
  __syncthreads();
  {
    const int w = wave, r = lane;
    const unsigned long long e = wlist[w][r];
    int rank = r;
#pragma unroll
    for (int w2 = 0; w2 < 4; ++w2) {
      if (w2 == w) continue;
      int lo = 0;
#pragma unroll
      for (int step = 32; step > 0; step >>= 1)
        if (lo + step <= KNB && wlist[w2][lo + step - 1] < e) lo += step;
      rank += lo;
    }
    if (rank < KNB) selk[rank] = e;
  }
  __syncthreads();
  if (t < KNB) {
    const unsigned long long e = selk[t];
    const int i = (int)(e & 0xffffffffu);
    const float* X = xf + (size_t)b * NPTS * 3;
    const size_t base = ((size_t)bm * KNB + t) * 6;
    gf0[base + 0] = P[i * 3 + 0] - sx;
    gf0[base + 1] = P[i * 3 + 1] - sy;
    gf0[base + 2] = P[i * 3 + 2] - sz;
    gf0[base + 3] = X[i * 3 + 0];
    gf0[base + 4] = X[i * 3 + 1];
    gf0[base + 5] = X[i * 3 + 2];
    sqsel[(size_t)bm * KNB + t] = __uint_as_float((unsigned)(e >> 32));
  }
}

// ================================================================ chain
__global__ __launch_bounds__(256) void l1_kernel(
    const float* __restrict__ gf0, const float* __restrict__ W0,
    const float* __restrict__ B0,
    float* __restrict__ psum, float* __restrict__ psq,
    float* __restrict__ y1pre) {
  __shared__ float in6[64 * 8];
  __shared__ float wbuf[384];
  __shared__ float out[64 * 65];
  const int blk = blockIdx.x;
  const int t = threadIdx.x;
  const float* G = gf0 + (size_t)blk * 384;
  for (int i = t; i < 384; i += 256) in6[(i / 6) * 8 + (i % 6)] = G[i];
  for (int i = t; i < 384; i += 256) wbuf[i] = W0[i];
  __syncthreads();
  const int r = t >> 2;
  const int c0 = (t & 3) * 16;
  float acc[16];
#pragma unroll
  for (int j = 0; j < 16; ++j) acc[j] = B0[c0 + j];
  for (int cin = 0; cin < 6; ++cin) {
    const float a = in6[r * 8 + cin];
#pragma unroll
    for (int j = 0; j < 16; ++j) acc[j] = fmaf(a, wbuf[cin * 64 + c0 + j], acc[j]);
  }
#pragma unroll
  for (int j = 0; j < 16; ++j) out[r * 65 + c0 + j] = acc[j];
  __syncthreads();
  if (t < 64) {
    float s = 0.f, q = 0.f;
    for (int r2 = 0; r2 < 64; ++r2) { const float v = out[r2 * 65 + t]; s += v; q += v * v; }
    psum[(size_t)t * NBLK + blk] = s;
    psq[(size_t)t * NBLK + blk] = q;
  }
  float* Y = y1pre + (size_t)blk * 4096;
  for (int i = t; i < 4096; i += 256) Y[i] = out[(i >> 6) * 65 + (i & 63)];
}

__global__ __launch_bounds__(256) void l2_kernel(
    const float* __restrict__ ypre, const float* __restrict__ sc,
    const float* __restrict__ sh, const float* __restrict__ W1,
    const float* __restrict__ B1,
    float* __restrict__ psum, float* __restrict__ psq,
    float* __restrict__ yout) {
  __shared__ float As[64 * 68];
  __shared__ float Bs[64 * 64];
  __shared__ float out[64 * 68];
  const int blk = blockIdx.x;
  const int t = threadIdx.x;
  const float* Y = ypre + (size_t)blk * 4096;
  for (int i = t; i < 4096; i += 256) {
    const int c = i & 63;
    As[(i >> 6) * 68 + c] = fmaxf(fmaf(Y[i], sc[c], sh[c]), 0.f);
  }
  for (int i = t; i < 4096; i += 256) Bs[i] = W1[i];
  __syncthreads();
  const int tr = t >> 4;
  const int tc4 = (t & 15) * 4;
  float acc[4][4];
#pragma unroll
  for (int s = 0; s < 4; ++s)
#pragma unroll
    for (int j = 0; j < 4; ++j) acc[s][j] = B1[tc4 + j];
  for (int k0 = 0; k0 < 64; k0 += 4) {
    float4 av[4];
#pragma unroll
    for (int s = 0; s < 4; ++s)
      av[s] = *reinterpret_cast<const float4*>(&As[(tr + 16 * s) * 68 + k0]);
#pragma unroll
    for (int kk = 0; kk < 4; ++kk) {
      const float4 bv = *reinterpret_cast<const float4*>(&Bs[(k0 + kk) * 64 + tc4]);
#pragma unroll
      for (int s = 0; s < 4; ++s) {
        const float a = (kk == 0) ? av[s].x : (kk == 1) ? av[s].y
                       : (kk == 2) ? av[s].z : av[s].w;
        acc[s][0] = fmaf(a, bv.x, acc[s][0]);
        acc[s][1] = fmaf(a, bv.y, acc[s][1]);
        acc[s][2] = fmaf(a, bv.z, acc[s][2]);
        acc[s][3] = fmaf(a, bv.w, acc[s][3]);
      }
    }
  }
#pragma unroll
  for (int s = 0; s < 4; ++s) {
    float4 o;
    o.x = acc[s][0]; o.y = acc[s][1]; o.z = acc[s][2]; o.w = acc[s][3];
    *reinterpret_cast<float4*>(&out[(tr + 16 * s) * 68 + tc4]) = o;
  }
  __syncthreads();
  if (t < 64) {
    float s = 0.f, q = 0.f;
    for (int r2 = 0; r2 < 64; ++r2) { const float v = out[r2 * 68 + t]; s += v; q += v * v; }
    psum[(size_t)t * NBLK + blk] = s;
    psq[(size_t)t * NBLK + blk] = q;
  }
  float* O = yout + (size_t)blk * 4096;
  for (int i = t; i < 4096; i += 256) O[i] = out[(i >> 6) * 68 + (i & 63)];
}

// L3: BN2+ReLU on load, 64x128 GEMM in 2 halves, stats as before, PLUS the
// radius-masked PRE-BN max per output channel -> x1mx (monotonicity: BN3 scale
// >0 and relu are weakly monotone, so max(act(y)) == act(max(y)) bit-exactly;
// row 0 (the point itself, distance 0) is always unmasked). Eliminates the
// 67MB y3pre write + re-read.
__global__ __launch_bounds__(256) void l3_kernel(
    const float* __restrict__ ypre, const float* __restrict__ sc,
    const float* __restrict__ sh, const float* __restrict__ W2,
    const float* __restrict__ B2, const float* __restrict__ sqsel,
    float* __restrict__ psum, float* __restrict__ psq,
    float* __restrict__ x1mx) {
  __shared__ float As[64 * 68];
  __shared__ float Bs[64 * 64];
  __shared__ float out[64 * 68];
  __shared__ float sqs[64];
  const int blk = blockIdx.x;
  const int t = threadIdx.x;
  const float* Y = ypre + (size_t)blk * 4096;
  if (t < 64) sqs[t] = sqsel[(size_t)blk * 64 + t];
  for (int i = t; i < 4096; i += 256) {
    const int c = i & 63;
    As[(i >> 6) * 68 + c] = fmaxf(fmaf(Y[i], sc[c], sh[c]), 0.f);
  }
  const int tr = t >> 4;
  const int tc4 = (t & 15) * 4;
  for (int hc = 0; hc < 2; ++hc) {
    __syncthreads();
    for (int i = t; i < 4096; i += 256)
      Bs[i] = W2[(i >> 6) * 128 + hc * 64 + (i & 63)];
    __syncthreads();
    float acc[4][4];
#pragma unroll
    for (int s = 0; s < 4; ++s)
#pragma unroll
      for (int j = 0; j < 4; ++j) acc[s][j] = B2[hc * 64 + tc4 + j];
    for (int k0 = 0; k0 < 64; k0 += 4) {
      float4 av[4];
#pragma unroll
      for (int s = 0; s < 4; ++s)
        av[s] = *reinterpret_cast<const float4*>(&As[(tr + 16 * s) * 68 + k0]);
#pragma unroll
      for (int kk = 0; kk < 4; ++kk) {
        const float4 bv = *reinterpret_cast<const float4*>(&Bs[(k0 + kk) * 64 + tc4]);
#pragma unroll
        for (int s = 0; s < 4; ++s) {
          const float a = (kk == 0) ? av[s].x : (kk == 1) ? av[s].y
                         : (kk == 2) ? av[s].z : av[s].w;
          acc[s][0] = fmaf(a, bv.x, acc[s][0]);
          acc[s][1] = fmaf(a, bv.y, acc[s][1]);
          acc[s][2] = fmaf(a, bv.z, acc[s][2]);
          acc[s][3] = fmaf(a, bv.w, acc[s][3]);
        }
      }
    }
#pragma unroll
    for (int s = 0; s < 4; ++s) {
      float4 o;
      o.x = acc[s][0]; o.y = acc[s][1]; o.z = acc[s][2]; o.w = acc[s][3];
      *reinterpret_cast<float4*>(&out[(tr + 16 * s) * 68 + tc4]) = o;
    }
    __syncthreads();
    if (t < 64) {
      float s = 0.f, q = 0.f;
      float my = -3.402823466e+38f;
      for (int r2 = 0; r2 < 64; ++r2) {
        const float v = out[r2 * 68 + t];
        s += v; q += v * v;
        if (sqs[r2] <= 0.16f) my = fmaxf(my, v);
      }
      psum[(size_t)(hc * 64 + t) * NBLK + blk] = s;
      psq[(size_t)(hc * 64 + t) * NBLK + blk] = q;
      x1mx[(size_t)blk * 128 + hc * 64 + t] = my;
    }
    __syncthreads();  // protect 'out' before next half overwrites
  }
}

// l4s1: BN3+ReLU on the PRE-BN masked max (exact by monotonicity), then the
// stage-1 first conv (identical fmaf order to the verified s1).
__global__ __launch_bounds__(128) void l4s1_kernel(
    const float* __restrict__ x1mx, const float* __restrict__ sc3,
    const float* __restrict__ sh3, const float* __restrict__ sp,
    const float* __restrict__ W, const float* __restrict__ bia,
    float* __restrict__ y1) {
  __shared__ float row[132];
  const int blk = blockIdx.x;
  const int t = threadIdx.x;
  const float my = x1mx[(size_t)blk * 128 + t];
  const float mx = fmaxf(fmaf(my, sc3[t], sh3[t]), 0.f);
  if (t < 3) row[t] = sp[(size_t)blk * 3 + t];
  row[3 + t] = mx;
  __syncthreads();
  float acc = bia[t];
  for (int cin = 0; cin < 131; ++cin) acc = fmaf(row[cin], W[(size_t)cin * 128 + t], acc);
  y1[(size_t)blk * 128 + t] = acc;
}

__global__ __launch_bounds__(256) void p_stats(const float* __restrict__ psum,
                                               const float* __restrict__ psq,
                                               float invN,
                                               const float* __restrict__ g,
                                               const float* __restrict__ be,
                                               float* __restrict__ sc,
                                               float* __restrict__ sh) {
  const int c = blockIdx.x;
  const int t = threadIdx.x;
  double s = 0.0, q = 0.0;
  for (int k = t; k < NBLK; k += 256) {
    s += (double)psum[(size_t)c * NBLK + k];
    q += (double)psq[(size_t)c * NBLK + k];
  }
  __shared__ double ss[256], qq[256];
  ss[t] = s;
  qq[t] = q;
  __syncthreads();
  for (int st = 128; st > 0; st >>= 1) {
    if (t < st) { ss[t] += ss[t + st]; qq[t] += qq[t + st]; }
    __syncthreads();
  }
  if (t == 0) {
    const double mean = ss[0] * (double)invN;
    double var = qq[0] * (double)invN - mean * mean;
    if (var < 0.0) var = 0.0;
    const float scl = (float)((double)g[c] / sqrt(var + 1e-5));
    sc[c] = scl;
    sh[c] = be[c] - (float)mean * scl;
  }
}

// ---------------------------------------------------------------- stage 1
__global__ __launch_bounds__(128) void s2_kernel(const float* __restrict__ y1,
                                                 const float* __restrict__ sc, const float* __restrict__ sh,
                                                 const float* __restrict__ W, const float* __restrict__ bia,
                                                 float* __restrict__ y2) {
  __shared__ float row[128];
  const int rowid = blockIdx.x;
  const int t = threadIdx.x;
  row[t] = fmaxf(fmaf(y1[(size_t)rowid * 128 + t], sc[t], sh[t]), 0.f);
  __syncthreads();
  float acc = bia[t];
  for (int cin = 0; cin < 128; ++cin) acc = fmaf(row[cin], W[(size_t)cin * 128 + t], acc);
  y2[(size_t)rowid * 128 + t] = acc;
}

__global__ __launch_bounds__(256) void s3_kernel(const float* __restrict__ y2,
                                                 const float* __restrict__ sc, const float* __restrict__ sh,
                                                 const float* __restrict__ W, const float* __restrict__ bia,
                                                 float* __restrict__ y3) {
  __shared__ float row[128];
  const int rowid = blockIdx.x;
  const int t = threadIdx.x;
  if (t < 128) row[t] = fmaxf(fmaf(y2[(size_t)rowid * 128 + t], sc[t], sh[t]), 0.f);
  __syncthreads();
  for (int h = 0; h < 2; ++h) {
    const int c = h * 256 + t;
    float acc = bia[c];
    for (int cin = 0; cin < 128; ++cin) acc = fmaf(row[cin], W[(size_t)cin * 512 + c], acc);
    y3[(size_t)rowid * 512 + c] = acc;
  }
}

__global__ __launch_bounds__(256) void s_stats(const float* __restrict__ y, int C, int rows,
                                               const float* __restrict__ g, const float* __restrict__ be,
                                               float* __restrict__ sc, float* __restrict__ sh) {
  const int c = blockIdx.x;
  const int t = threadIdx.x;
  double s = 0.0, q = 0.0;
  for (int r2 = t; r2 < rows; r2 += 256) {
    const double v = (double)y[(size_t)r2 * C + c];
    s += v;
    q += v * v;
  }
  __shared__ double ss[256], qq[256];
  ss[t] = s;
  qq[t] = q;
  __syncthreads();
  for (int st = 128; st > 0; st >>= 1) {
    if (t < st) { ss[t] += ss[t + st]; qq[t] += qq[t + st]; }
    __syncthreads();
  }
  if (t == 0) {
    const double mean = ss[0] / rows;
    double var = qq[0] / rows - mean * mean;
    if (var < 0.0) var = 0.0;
    const float scl = (float)((double)g[c] / sqrt(var + 1e-5));
    sc[c] = scl;
    sh[c] = be[c] - (float)mean * scl;
  }
}

__global__ __launch_bounds__(256) void s_stats_final(const float* __restrict__ y3,
                                                     const float* __restrict__ g,
                                                     const float* __restrict__ be,
                                                     float* __restrict__ out) {
  const int c = blockIdx.x;
  const int t = threadIdx.x;
  double s = 0.0, q = 0.0;
  for (int r2 = t; r2 < NBLK; r2 += 256) {
    const double v = (double)y3[(size_t)r2 * 512 + c];
    s += v;
    q += v * v;
  }
  __shared__ double ss[256], qq[256];
  __shared__ float sscl, sshv;
  ss[t] = s;
  qq[t] = q;
  __syncthreads();
  for (int st = 128; st > 0; st >>= 1) {
    if (t < st) { ss[t] += ss[t + st]; qq[t] += qq[t + st]; }
    __syncthreads();
  }
  if (t == 0) {
    const double mean = ss[0] / NBLK;
    double var = qq[0] / NBLK - mean * mean;
    if (var < 0.0) var = 0.0;
    const float scl = (float)((double)g[c] / sqrt(var + 1e-5));
    sscl = scl;
    sshv = be[c] - (float)mean * scl;
  }
  __syncthreads();
  const float scl = sscl, shv = sshv;
  float mx = -3.402823466e+38f;
  for (int k = 0; k < 8; ++k) {
    const int r = t * 8 + k;
    const float v = fmaxf(fmaf(y3[(size_t)r * 512 + c], scl, shv), 0.f);
    mx = fmaxf(mx, v);
  }
  __shared__ float pmax[256];
  pmax[t] = mx;
  __syncthreads();
  if (t < 16) {
    float m = -3.402823466e+38f;
    for (int j = 0; j < 16; ++j) m = fmaxf(m, pmax[t * 16 + j]);
    out[(size_t)t * 512 + c] = m;
  }
  if (c == 0 && t < 48) out[8192 + t] = 0.f;  // pos_out zeros
}

extern "C" void kernel_launch(void* const* d_in, const int* in_sizes, int n_in,
                              void* d_out, int out_size, void* d_ws, size_t ws_size,
                              hipStream_t stream) {
  const float* x    = (const float*)d_in[0];
  const float* pos  = (const float*)d_in[1];
  const float* W00  = (const float*)d_in[2];
  const float* b00  = (const float*)d_in[3];
  const float* g00  = (const float*)d_in[4];
  const float* be00 = (const float*)d_in[5];
  const float* W01  = (const float*)d_in[6];
  const float* b01  = (const float*)d_in[7];
  const float* g01  = (const float*)d_in[8];
  const float* be01 = (const float*)d_in[9];
  const float* W02  = (const float*)d_in[10];
  const float* b02  = (const float*)d_in[11];
  const float* g02  = (const float*)d_in[12];
  const float* be02 = (const float*)d_in[13];
  const float* W10  = (const float*)d_in[14];
  const float* b10  = (const float*)d_in[15];
  const float* g10  = (const float*)d_in[16];
  const float* be10 = (const float*)d_in[17];
  const float* W11  = (const float*)d_in[18];
  const float* b11  = (const float*)d_in[19];
  const float* g11  = (const float*)d_in[20];
  const float* be11 = (const float*)d_in[21];
  const float* W12  = (const float*)d_in[22];
  const float* b12  = (const float*)d_in[23];
  const float* g12  = (const float*)d_in[24];
  const float* be12 = (const float*)d_in[25];

  float* w = (float*)d_ws;
  float* sp    = w;                  // 6144
  float* gf0   = sp + 6144;          // 786432
  float* sqsel = gf0 + 786432;       // 131072
  float* x1mx  = sqsel + 131072;     // 262144 (pre-BN masked maxima)
  float* parts = x1mx + 262144;      // 524288
  float* psum  = parts;
  float* psq   = parts + 128 * NBLK;
  float* st    = parts + 524288;     // 2048
  float* sc1 = st + 0,    *sh1 = st + 64;
  float* sc2 = st + 128,  *sh2 = st + 192;
  float* sc3 = st + 256,  *sh3 = st + 384;
  float* t1sc = st + 512, *t1sh = st + 640;
  float* t2sc = st + 768, *t2sh = st + 896;
  float* y1s = st + 2048;            // 262144
  float* y2s = y1s + 262144;         // 262144
  float* y3s = y2s + 262144;         // 1048576
  const size_t BASE = 3284992;
  float* y1pre = w + BASE;                       // 8388608
  float* y2pre = y1pre + 8388608;                // 8388608

  fps_kernel<<<BATCH, 1024, NPTS * sizeof(float4), stream>>>(pos, sp);
  knn_kernel<<<BATCH * MS, 256, 0, stream>>>(pos, x, sp, gf0, sqsel);

  const float invN0 = 1.0f / (float)(NBLK * KNB);  // 1/131072
  l1_kernel<<<NBLK, 256, 0, stream>>>(gf0, W00, b00, psum, psq, y1pre);
  p_stats<<<64, 256, 0, stream>>>(psum, psq, invN0, g00, be00, sc1, sh1);
  l2_kernel<<<NBLK, 256, 0, stream>>>(y1pre, sc1, sh1, W01, b01, psum, psq, y2pre);
  p_stats<<<64, 256, 0, stream>>>(psum, psq, invN0, g01, be01, sc2, sh2);
  l3_kernel<<<NBLK, 256, 0, stream>>>(y2pre, sc2, sh2, W02, b02, sqsel, psum, psq, x1mx);
  p_stats<<<128, 256, 0, stream>>>(psum, psq, invN0, g02, be02, sc3, sh3);
  l4s1_kernel<<<NBLK, 128, 0, stream>>>(x1mx, sc3, sh3, sp, W10, b10, y1s);

  s_stats<<<128, 256, 0, stream>>>(y1s, 128, NBLK, g10, be10, t1sc, t1sh);
  s2_kernel<<<NBLK, 128, 0, stream>>>(y1s, t1sc, t1sh, W11, b11, y2s);
  s_stats<<<128, 256, 0, stream>>>(y2s, 128, NBLK, g11, be11, t2sc, t2sh);
  s3_kernel<<<NBLK, 256, 0, stream>>>(y2s, t2sc, t2sh, W12, b12, y3s);
  s_stats_final<<<512, 256, 0, stream>>>(y3s, g12, be12, (float*)d_out);
}